// Round 1
// baseline (1119.994 us; speedup 1.0000x reference)
//
#include <hip/hip_runtime.h>

#define HIGH 384
#define LOWD 64
#define EMB  128
#define HID  128

// ---------------- utility kernels ----------------

__global__ void k_zero_int(int* p, int n) {
    int i = blockIdx.x * 256 + threadIdx.x;
    if (i < n) p[i] = 0;
}

__global__ void k_hist(const int* __restrict__ dst, int E, int* __restrict__ cnt) {
    int e = blockIdx.x * 256 + threadIdx.x;
    if (e < E) atomicAdd(&cnt[dst[e]], 1);
}

__global__ void k_dis(const int* __restrict__ cnt, float* __restrict__ dis, int N) {
    int i = blockIdx.x * 256 + threadIdx.x;
    if (i < N) dis[i] = rsqrtf((float)cnt[i] + 1.0f);
}

// ---------------- scan (3-kernel) ----------------

__global__ void k_scan1(const int* __restrict__ cnt, int N, int* __restrict__ bsums) {
    __shared__ int sh[256];
    int t = threadIdx.x;
    int base = blockIdx.x * 1024 + t * 4;
    int s = 0;
#pragma unroll
    for (int j = 0; j < 4; j++) { int idx = base + j; s += (idx < N) ? cnt[idx] : 0; }
    sh[t] = s; __syncthreads();
    for (int off = 128; off > 0; off >>= 1) {
        if (t < off) sh[t] += sh[t + off];
        __syncthreads();
    }
    if (t == 0) bsums[blockIdx.x] = sh[0];
}

__global__ void k_scan2(int* bsums, int nb) {
    if (threadIdx.x == 0 && blockIdx.x == 0) {
        int run = 0;
        for (int i = 0; i < nb; i++) { int v = bsums[i]; bsums[i] = run; run += v; }
    }
}

__global__ void k_scan3(const int* __restrict__ cnt, int N, const int* __restrict__ bsums,
                        int* __restrict__ row_start, int* __restrict__ fcur, int E) {
    __shared__ int sh[256];
    int t = threadIdx.x;
    int base = blockIdx.x * 1024 + t * 4;
    int v[4]; int s = 0;
#pragma unroll
    for (int j = 0; j < 4; j++) { int idx = base + j; v[j] = (idx < N) ? cnt[idx] : 0; s += v[j]; }
    sh[t] = s; __syncthreads();
    int x = s;
    for (int off = 1; off < 256; off <<= 1) {
        int y = (t >= off) ? sh[t - off] : 0;
        __syncthreads();
        x += y; sh[t] = x;
        __syncthreads();
    }
    int thr_excl = x - s;
    int run = bsums[blockIdx.x] + thr_excl;
#pragma unroll
    for (int j = 0; j < 4; j++) {
        int idx = base + j;
        if (idx < N) { row_start[idx] = run; fcur[idx] = run; }
        run += v[j];
    }
    if (blockIdx.x == 0 && t == 0) row_start[N] = E;
}

__global__ void k_fill(const int* __restrict__ src, const int* __restrict__ dst, int E,
                       int* __restrict__ fcur, int* __restrict__ csr) {
    int e = blockIdx.x * 256 + threadIdx.x;
    if (e < E) {
        int d = dst[e];
        int pos = atomicAdd(&fcur[d], 1);
        csr[pos] = src[e];
    }
}

// ---------------- fused GEMM: C[M x 128] = [A1|A2] @ W  (+bias) (*dis) (relu) ----------------
// BM=64, BN=128, BK=32, 256 threads, 4x8 micro-tile per thread.

template<bool BIAS, bool RELU, bool SCALE>
__global__ __launch_bounds__(256) void k_gemm(
    const float* __restrict__ A1, int K1,
    const float* __restrict__ A2, int K2,
    const float* __restrict__ W,
    const float* __restrict__ bias,
    const float* __restrict__ dis,
    float* __restrict__ C, int M)
{
    __shared__ float As[32][68];   // [k][m], padded
    __shared__ float Ws[32][132];  // [k][n], padded

    const int tid = threadIdx.x;
    const int tx = tid & 15;       // 0..15 -> cols tx*8..+7
    const int ty = tid >> 4;       // 0..15 -> rows ty*4..+3
    const int blockRow = blockIdx.x * 64;
    const int K = K1 + K2;

    float acc[4][8];
#pragma unroll
    for (int i = 0; i < 4; i++)
#pragma unroll
        for (int j = 0; j < 8; j++) acc[i][j] = 0.f;

    const int la_m = tid >> 3;        // 0..31
    const int la_c = (tid & 7) * 4;   // 0..28
    const int lw_j = (tid & 31) * 4;  // 0..124
    const int lw_k = tid >> 5;        // 0..7

    for (int k0 = 0; k0 < K; k0 += 32) {
        const float* A; int lda, kcol;
        if (k0 < K1) { A = A1; lda = K1; kcol = k0; }
        else         { A = A2; lda = K2; kcol = k0 - K1; }

#pragma unroll
        for (int h = 0; h < 2; h++) {
            int m = la_m + h * 32;
            int row = blockRow + m; if (row >= M) row = M - 1;
            const float4 av = *(const float4*)&A[(size_t)row * lda + kcol + la_c];
            As[la_c + 0][m] = av.x; As[la_c + 1][m] = av.y;
            As[la_c + 2][m] = av.z; As[la_c + 3][m] = av.w;
        }
#pragma unroll
        for (int h = 0; h < 4; h++) {
            int kk = lw_k + h * 8;
            const float4 wv = *(const float4*)&W[(size_t)(k0 + kk) * 128 + lw_j];
            *(float4*)&Ws[kk][lw_j] = wv;
        }
        __syncthreads();

#pragma unroll
        for (int kk = 0; kk < 32; kk++) {
            float4 a  = *(const float4*)&As[kk][ty * 4];
            float4 w0 = *(const float4*)&Ws[kk][tx * 8];
            float4 w1 = *(const float4*)&Ws[kk][tx * 8 + 4];
            float av[4] = {a.x, a.y, a.z, a.w};
            float wv[8] = {w0.x, w0.y, w0.z, w0.w, w1.x, w1.y, w1.z, w1.w};
#pragma unroll
            for (int i = 0; i < 4; i++)
#pragma unroll
                for (int j = 0; j < 8; j++)
                    acc[i][j] = fmaf(av[i], wv[j], acc[i][j]);
        }
        __syncthreads();
    }

#pragma unroll
    for (int i = 0; i < 4; i++) {
        int row = blockRow + ty * 4 + i;
        if (row < M) {
            float scale = SCALE ? dis[row] : 1.0f;
            float out[8];
#pragma unroll
            for (int j = 0; j < 8; j++) {
                float v = acc[i][j];
                if (BIAS) v += bias[tx * 8 + j];
                if (SCALE) v *= scale;
                if (RELU) v = fmaxf(v, 0.f);
                out[j] = v;
            }
            float4* cp = (float4*)&C[(size_t)row * 128 + tx * 8];
            cp[0] = make_float4(out[0], out[1], out[2], out[3]);
            cp[1] = make_float4(out[4], out[5], out[6], out[7]);
        }
    }
}

// ---------------- gather: h[n] = relu(dis[n] * (sum_{s in N(n)} xls[s] + xls[n]) + b) ----------------

__global__ __launch_bounds__(256) void k_gather(
    const float* __restrict__ xls, const int* __restrict__ row_start,
    const int* __restrict__ csr, const float* __restrict__ dis,
    const float* __restrict__ bias, float* __restrict__ h, int N)
{
    int wave = threadIdx.x >> 6;
    int lane = threadIdx.x & 63;
    int n = blockIdx.x * 4 + wave;
    if (n >= N) return;
    int jb = row_start[n], je = row_start[n + 1];
    float2 acc = *(const float2*)&xls[(size_t)n * 128 + lane * 2];  // self-loop term
    int j = jb;
    for (; j + 1 < je; j += 2) {
        int s0 = csr[j], s1 = csr[j + 1];
        float2 v0 = *(const float2*)&xls[(size_t)s0 * 128 + lane * 2];
        float2 v1 = *(const float2*)&xls[(size_t)s1 * 128 + lane * 2];
        acc.x += v0.x + v1.x; acc.y += v0.y + v1.y;
    }
    if (j < je) {
        int s = csr[j];
        float2 v = *(const float2*)&xls[(size_t)s * 128 + lane * 2];
        acc.x += v.x; acc.y += v.y;
    }
    float d = dis[n];
    float o0 = fmaxf(fmaf(d, acc.x, bias[lane * 2 + 0]), 0.f);
    float o1 = fmaxf(fmaf(d, acc.y, bias[lane * 2 + 1]), 0.f);
    *(float2*)&h[(size_t)n * 128 + lane * 2] = make_float2(o0, o1);
}

// ---------------- final: logits + log_softmax ----------------

__global__ __launch_bounds__(256) void k_final(
    const float* __restrict__ h, const float* __restrict__ Wl,
    const float* __restrict__ bl, float* __restrict__ out, int N)
{
    int wave = threadIdx.x >> 6, lane = threadIdx.x & 63;
    int n = blockIdx.x * 4 + wave;
    if (n >= N) return;
    float h0 = h[(size_t)n * 128 + lane];
    float h1 = h[(size_t)n * 128 + lane + 64];
    float p0 = h0 * Wl[lane * 2 + 0] + h1 * Wl[(lane + 64) * 2 + 0];
    float p1 = h0 * Wl[lane * 2 + 1] + h1 * Wl[(lane + 64) * 2 + 1];
#pragma unroll
    for (int off = 32; off > 0; off >>= 1) {
        p0 += __shfl_down(p0, off);
        p1 += __shfl_down(p1, off);
    }
    if (lane == 0) {
        float z0 = p0 + bl[0], z1 = p1 + bl[1];
        float m = fmaxf(z0, z1);
        float ls = m + logf(expf(z0 - m) + expf(z1 - m));
        out[(size_t)n * 2 + 0] = z0 - ls;
        out[(size_t)n * 2 + 1] = z1 - ls;
    }
}

// ---------------- launch ----------------

extern "C" void kernel_launch(void* const* d_in, const int* in_sizes, int n_in,
                              void* d_out, int out_size, void* d_ws, size_t ws_size,
                              hipStream_t stream) {
    const float* high  = (const float*)d_in[0];
    const float* low   = (const float*)d_in[1];
    const int*   ei    = (const int*)d_in[2];
    const float* W_emb = (const float*)d_in[3];
    const float* b_emb = (const float*)d_in[4];
    const float* W1    = (const float*)d_in[5];
    const float* b1    = (const float*)d_in[6];
    const float* W2    = (const float*)d_in[7];
    const float* b2    = (const float*)d_in[8];
    const float* Wl    = (const float*)d_in[9];
    const float* bl    = (const float*)d_in[10];

    int N = in_sizes[0] / HIGH;
    int E = in_sizes[2] / 2;
    const int* srcp = ei;
    const int* dstp = ei + E;
    float* out = (float*)d_out;

    char* ws = (char*)d_ws;
    size_t off = 0;
    auto alloc = [&](size_t b) { size_t o = off; off += (b + 255) & ~(size_t)255; return o; };
    float* dis       = (float*)(ws + alloc((size_t)N * 4));
    int*   cnt       = (int*)  (ws + alloc((size_t)N * 4));
    int*   row_start = (int*)  (ws + alloc((size_t)(N + 1) * 4));
    int*   fcur      = (int*)  (ws + alloc((size_t)N * 4));
    int*   bsums     = (int*)  (ws + alloc(4096));
    int*   csr       = (int*)  (ws + alloc((size_t)E * 4));
    float* bufA      = (float*)(ws + alloc((size_t)N * HID * 4));
    float* bufB      = (float*)(ws + alloc((size_t)N * HID * 4));
    (void)ws_size; (void)n_in; (void)out_size;

    int nb = (N + 1023) / 1024;
    int mt = (N + 63) / 64;

    k_zero_int<<<(N + 255) / 256, 256, 0, stream>>>(cnt, N);
    k_hist<<<(E + 255) / 256, 256, 0, stream>>>(dstp, E, cnt);
    k_dis<<<(N + 255) / 256, 256, 0, stream>>>(cnt, dis, N);
    k_scan1<<<nb, 256, 0, stream>>>(cnt, N, bsums);
    k_scan2<<<1, 64, 0, stream>>>(bsums, nb);
    k_scan3<<<nb, 256, 0, stream>>>(cnt, N, bsums, row_start, fcur, E);
    k_fill<<<(E + 255) / 256, 256, 0, stream>>>(srcp, dstp, E, fcur, csr);

    // low_emb = relu(low @ W_emb + b_emb)            -> bufA
    k_gemm<true, true, false><<<mt, 256, 0, stream>>>(low, LOWD, nullptr, 0, W_emb, b_emb, nullptr, bufA, N);
    // xls1 = ([high | low_emb] @ W1) * dis           -> bufB
    k_gemm<false, false, true><<<mt, 256, 0, stream>>>(high, HIGH, bufA, EMB, W1, nullptr, dis, bufB, N);
    // h1 = relu(dis * (gather(xls1) + self) + b1)    -> bufA
    k_gather<<<(N + 3) / 4, 256, 0, stream>>>(bufB, row_start, csr, dis, b1, bufA, N);
    // xls2 = (h1 @ W2) * dis                         -> bufB
    k_gemm<false, false, true><<<mt, 256, 0, stream>>>(bufA, HID, nullptr, 0, W2, nullptr, dis, bufB, N);
    // h2 = relu(dis * (gather(xls2) + self) + b2)    -> bufA
    k_gather<<<(N + 3) / 4, 256, 0, stream>>>(bufB, row_start, csr, dis, b2, bufA, N);
    // out = log_softmax(h2 @ W_lin + b_lin)
    k_final<<<(N + 3) / 4, 256, 0, stream>>>(bufA, Wl, bl, out, N);
}

// Round 2
// 966.654 us; speedup vs baseline: 1.1586x; 1.1586x over previous
//
#include <hip/hip_runtime.h>

#define HIGH 384
#define LOWD 64
#define EMB  128
#define HID  128

// Binned CSR build: bin = dst >> 8. Requires N <= 131072 (src packs in 17 bits).
#define BINSHIFT 8
#define SRCBITS  17
#define SRCMASK  0x1FFFF
#define NBLK     512   // blocks for binhist/binscatter

// ---------------- utility kernels ----------------

__global__ void k_zero_int(int* p, int n) {
    int i = blockIdx.x * 256 + threadIdx.x;
    if (i < n) p[i] = 0;
}

__global__ void k_dis(const int* __restrict__ cnt, float* __restrict__ dis, int N) {
    int i = blockIdx.x * 256 + threadIdx.x;
    if (i < N) dis[i] = rsqrtf((float)cnt[i] + 1.0f);
}

// ---------------- binned edge partition ----------------

// Per-block LDS histogram over bins -> cnts[bin * NBLK + blk]
__global__ __launch_bounds__(256) void k_binhist(const int* __restrict__ dst, int E,
                                                 int* __restrict__ cnts, int NB) {
    __shared__ int hist[512];
    for (int b = threadIdx.x; b < NB; b += 256) hist[b] = 0;
    __syncthreads();
    int CH = (E + gridDim.x - 1) / gridDim.x;
    int e0 = blockIdx.x * CH;
    int e1 = min(E, e0 + CH);
    for (int e = e0 + threadIdx.x; e < e1; e += 256)
        atomicAdd(&hist[dst[e] >> BINSHIFT], 1);
    __syncthreads();
    for (int b = threadIdx.x; b < NB; b += 256)
        cnts[b * NBLK + blockIdx.x] = hist[b];
}

// Scatter edges into bin-ordered packed array. cnts holds the exclusive scan.
__global__ __launch_bounds__(256) void k_binscatter(const int* __restrict__ src,
                                                    const int* __restrict__ dst, int E,
                                                    const int* __restrict__ cnts,
                                                    unsigned int* __restrict__ packed, int NB) {
    __shared__ int cur[512];
    for (int b = threadIdx.x; b < NB; b += 256) cur[b] = cnts[b * NBLK + blockIdx.x];
    __syncthreads();
    int CH = (E + gridDim.x - 1) / gridDim.x;
    int e0 = blockIdx.x * CH;
    int e1 = min(E, e0 + CH);
    for (int e = e0 + threadIdx.x; e < e1; e += 256) {
        int d = dst[e];
        int s = src[e];
        int bin = d >> BINSHIFT;
        int pos = atomicAdd(&cur[bin], 1);
        packed[pos] = (unsigned int)s | ((unsigned int)(d & 255) << SRCBITS);
    }
}

// Degree histogram over binned edges: one block per bin, atomics in a 1KB window.
__global__ __launch_bounds__(256) void k_hist2(const unsigned int* __restrict__ packed,
                                               const int* __restrict__ cnts, int E,
                                               int* __restrict__ cnt, int NB) {
    int b = blockIdx.x;
    int begin = cnts[b * NBLK];
    int end = (b + 1 < NB) ? cnts[(b + 1) * NBLK] : E;
    int base = b << BINSHIFT;
    for (int e = begin + threadIdx.x; e < end; e += 256) {
        unsigned int p = packed[e];
        atomicAdd(&cnt[base + (p >> SRCBITS)], 1);
    }
}

// CSR fill over binned edges: fcur atomics in 1KB window, csr writes in ~32KB window.
__global__ __launch_bounds__(256) void k_fill2(const unsigned int* __restrict__ packed,
                                               const int* __restrict__ cnts, int E,
                                               int* __restrict__ fcur, int* __restrict__ csr,
                                               int NB) {
    int b = blockIdx.x;
    int begin = cnts[b * NBLK];
    int end = (b + 1 < NB) ? cnts[(b + 1) * NBLK] : E;
    int base = b << BINSHIFT;
    for (int e = begin + threadIdx.x; e < end; e += 256) {
        unsigned int p = packed[e];
        int d = base + (int)(p >> SRCBITS);
        int pos = atomicAdd(&fcur[d], 1);
        csr[pos] = (int)(p & SRCMASK);
    }
}

// ---------------- scan (3-kernel, generic) ----------------

__global__ void k_scan1(const int* __restrict__ in, int n, int* __restrict__ bsums) {
    __shared__ int sh[256];
    int t = threadIdx.x;
    int base = blockIdx.x * 1024 + t * 4;
    int s = 0;
#pragma unroll
    for (int j = 0; j < 4; j++) { int idx = base + j; s += (idx < n) ? in[idx] : 0; }
    sh[t] = s; __syncthreads();
    for (int off = 128; off > 0; off >>= 1) {
        if (t < off) sh[t] += sh[t + off];
        __syncthreads();
    }
    if (t == 0) bsums[blockIdx.x] = sh[0];
}

__global__ void k_scan2(int* bsums, int nb) {
    if (threadIdx.x == 0 && blockIdx.x == 0) {
        int run = 0;
        for (int i = 0; i < nb; i++) { int v = bsums[i]; bsums[i] = run; run += v; }
    }
}

// In-place exclusive scan finish (each thread reads its 4 before writing).
__global__ void k_scan3_flat(int* __restrict__ data, int n, const int* __restrict__ bsums) {
    __shared__ int sh[256];
    int t = threadIdx.x;
    int base = blockIdx.x * 1024 + t * 4;
    int v[4]; int s = 0;
#pragma unroll
    for (int j = 0; j < 4; j++) { int idx = base + j; v[j] = (idx < n) ? data[idx] : 0; s += v[j]; }
    sh[t] = s; __syncthreads();
    int x = s;
    for (int off = 1; off < 256; off <<= 1) {
        int y = (t >= off) ? sh[t - off] : 0;
        __syncthreads();
        x += y; sh[t] = x;
        __syncthreads();
    }
    int run = bsums[blockIdx.x] + (x - s);
#pragma unroll
    for (int j = 0; j < 4; j++) {
        int idx = base + j;
        if (idx < n) data[idx] = run;
        run += v[j];
    }
}

// Exclusive scan -> row_start (+tail) and fcur.
__global__ void k_scan3_rows(const int* __restrict__ cnt, int N, const int* __restrict__ bsums,
                             int* __restrict__ row_start, int* __restrict__ fcur, int E) {
    __shared__ int sh[256];
    int t = threadIdx.x;
    int base = blockIdx.x * 1024 + t * 4;
    int v[4]; int s = 0;
#pragma unroll
    for (int j = 0; j < 4; j++) { int idx = base + j; v[j] = (idx < N) ? cnt[idx] : 0; s += v[j]; }
    sh[t] = s; __syncthreads();
    int x = s;
    for (int off = 1; off < 256; off <<= 1) {
        int y = (t >= off) ? sh[t - off] : 0;
        __syncthreads();
        x += y; sh[t] = x;
        __syncthreads();
    }
    int run = bsums[blockIdx.x] + (x - s);
#pragma unroll
    for (int j = 0; j < 4; j++) {
        int idx = base + j;
        if (idx < N) { row_start[idx] = run; fcur[idx] = run; }
        run += v[j];
    }
    if (blockIdx.x == 0 && t == 0) row_start[N] = E;
}

// ---------------- fused GEMM: C[M x 128] = [A1|A2] @ W  (+bias) (*dis) (relu) ----------------

template<bool BIAS, bool RELU, bool SCALE>
__global__ __launch_bounds__(256) void k_gemm(
    const float* __restrict__ A1, int K1,
    const float* __restrict__ A2, int K2,
    const float* __restrict__ W,
    const float* __restrict__ bias,
    const float* __restrict__ dis,
    float* __restrict__ C, int M)
{
    __shared__ float As[32][68];   // [k][m], padded
    __shared__ float Ws[32][132];  // [k][n], padded

    const int tid = threadIdx.x;
    const int tx = tid & 15;
    const int ty = tid >> 4;
    const int blockRow = blockIdx.x * 64;
    const int K = K1 + K2;

    float acc[4][8];
#pragma unroll
    for (int i = 0; i < 4; i++)
#pragma unroll
        for (int j = 0; j < 8; j++) acc[i][j] = 0.f;

    const int la_m = tid >> 3;
    const int la_c = (tid & 7) * 4;
    const int lw_j = (tid & 31) * 4;
    const int lw_k = tid >> 5;

    for (int k0 = 0; k0 < K; k0 += 32) {
        const float* A; int lda, kcol;
        if (k0 < K1) { A = A1; lda = K1; kcol = k0; }
        else         { A = A2; lda = K2; kcol = k0 - K1; }

#pragma unroll
        for (int h = 0; h < 2; h++) {
            int m = la_m + h * 32;
            int row = blockRow + m; if (row >= M) row = M - 1;
            const float4 av = *(const float4*)&A[(size_t)row * lda + kcol + la_c];
            As[la_c + 0][m] = av.x; As[la_c + 1][m] = av.y;
            As[la_c + 2][m] = av.z; As[la_c + 3][m] = av.w;
        }
#pragma unroll
        for (int h = 0; h < 4; h++) {
            int kk = lw_k + h * 8;
            const float4 wv = *(const float4*)&W[(size_t)(k0 + kk) * 128 + lw_j];
            *(float4*)&Ws[kk][lw_j] = wv;
        }
        __syncthreads();

#pragma unroll
        for (int kk = 0; kk < 32; kk++) {
            float4 a  = *(const float4*)&As[kk][ty * 4];
            float4 w0 = *(const float4*)&Ws[kk][tx * 8];
            float4 w1 = *(const float4*)&Ws[kk][tx * 8 + 4];
            float av[4] = {a.x, a.y, a.z, a.w};
            float wv[8] = {w0.x, w0.y, w0.z, w0.w, w1.x, w1.y, w1.z, w1.w};
#pragma unroll
            for (int i = 0; i < 4; i++)
#pragma unroll
                for (int j = 0; j < 8; j++)
                    acc[i][j] = fmaf(av[i], wv[j], acc[i][j]);
        }
        __syncthreads();
    }

#pragma unroll
    for (int i = 0; i < 4; i++) {
        int row = blockRow + ty * 4 + i;
        if (row < M) {
            float scale = SCALE ? dis[row] : 1.0f;
            float out[8];
#pragma unroll
            for (int j = 0; j < 8; j++) {
                float v = acc[i][j];
                if (BIAS) v += bias[tx * 8 + j];
                if (SCALE) v *= scale;
                if (RELU) v = fmaxf(v, 0.f);
                out[j] = v;
            }
            float4* cp = (float4*)&C[(size_t)row * 128 + tx * 8];
            cp[0] = make_float4(out[0], out[1], out[2], out[3]);
            cp[1] = make_float4(out[4], out[5], out[6], out[7]);
        }
    }
}

// ---------------- gather: h[n] = relu(dis[n] * (sum_{s in N(n)} xls[s] + xls[n]) + b) ----------------

__global__ __launch_bounds__(256) void k_gather(
    const float* __restrict__ xls, const int* __restrict__ row_start,
    const int* __restrict__ csr, const float* __restrict__ dis,
    const float* __restrict__ bias, float* __restrict__ h, int N)
{
    int wave = threadIdx.x >> 6;
    int lane = threadIdx.x & 63;
    int n = blockIdx.x * 4 + wave;
    if (n >= N) return;
    int jb = row_start[n], je = row_start[n + 1];
    float2 acc = *(const float2*)&xls[(size_t)n * 128 + lane * 2];  // self-loop term
    int j = jb;
    for (; j + 1 < je; j += 2) {
        int s0 = csr[j], s1 = csr[j + 1];
        float2 v0 = *(const float2*)&xls[(size_t)s0 * 128 + lane * 2];
        float2 v1 = *(const float2*)&xls[(size_t)s1 * 128 + lane * 2];
        acc.x += v0.x + v1.x; acc.y += v0.y + v1.y;
    }
    if (j < je) {
        int s = csr[j];
        float2 v = *(const float2*)&xls[(size_t)s * 128 + lane * 2];
        acc.x += v.x; acc.y += v.y;
    }
    float d = dis[n];
    float o0 = fmaxf(fmaf(d, acc.x, bias[lane * 2 + 0]), 0.f);
    float o1 = fmaxf(fmaf(d, acc.y, bias[lane * 2 + 1]), 0.f);
    *(float2*)&h[(size_t)n * 128 + lane * 2] = make_float2(o0, o1);
}

// ---------------- final: logits + log_softmax ----------------

__global__ __launch_bounds__(256) void k_final(
    const float* __restrict__ h, const float* __restrict__ Wl,
    const float* __restrict__ bl, float* __restrict__ out, int N)
{
    int wave = threadIdx.x >> 6, lane = threadIdx.x & 63;
    int n = blockIdx.x * 4 + wave;
    if (n >= N) return;
    float h0 = h[(size_t)n * 128 + lane];
    float h1 = h[(size_t)n * 128 + lane + 64];
    float p0 = h0 * Wl[lane * 2 + 0] + h1 * Wl[(lane + 64) * 2 + 0];
    float p1 = h0 * Wl[lane * 2 + 1] + h1 * Wl[(lane + 64) * 2 + 1];
#pragma unroll
    for (int off = 32; off > 0; off >>= 1) {
        p0 += __shfl_down(p0, off);
        p1 += __shfl_down(p1, off);
    }
    if (lane == 0) {
        float z0 = p0 + bl[0], z1 = p1 + bl[1];
        float m = fmaxf(z0, z1);
        float ls = m + logf(expf(z0 - m) + expf(z1 - m));
        out[(size_t)n * 2 + 0] = z0 - ls;
        out[(size_t)n * 2 + 1] = z1 - ls;
    }
}

// ---------------- launch ----------------

extern "C" void kernel_launch(void* const* d_in, const int* in_sizes, int n_in,
                              void* d_out, int out_size, void* d_ws, size_t ws_size,
                              hipStream_t stream) {
    const float* high  = (const float*)d_in[0];
    const float* low   = (const float*)d_in[1];
    const int*   ei    = (const int*)d_in[2];
    const float* W_emb = (const float*)d_in[3];
    const float* b_emb = (const float*)d_in[4];
    const float* W1    = (const float*)d_in[5];
    const float* b1    = (const float*)d_in[6];
    const float* W2    = (const float*)d_in[7];
    const float* b2    = (const float*)d_in[8];
    const float* Wl    = (const float*)d_in[9];
    const float* bl    = (const float*)d_in[10];

    int N = in_sizes[0] / HIGH;
    int E = in_sizes[2] / 2;
    const int* srcp = ei;
    const int* dstp = ei + E;
    float* out = (float*)d_out;

    int NB = (N + 255) >> BINSHIFT;      // 391 bins
    int NSCAN = NB * NBLK;               // 200192

    char* ws = (char*)d_ws;
    size_t off = 0;
    auto alloc = [&](size_t b) { size_t o = off; off += (b + 255) & ~(size_t)255; return o; };
    float* dis       = (float*)(ws + alloc((size_t)N * 4));
    int*   cnt       = (int*)  (ws + alloc((size_t)N * 4));
    int*   row_start = (int*)  (ws + alloc((size_t)(N + 1) * 4));
    int*   fcur      = (int*)  (ws + alloc((size_t)N * 4));
    int*   bsums     = (int*)  (ws + alloc(4096));
    int*   cnts      = (int*)  (ws + alloc((size_t)NSCAN * 4));
    unsigned int* packed = (unsigned int*)(ws + alloc((size_t)E * 4));
    int*   csr       = (int*)  (ws + alloc((size_t)E * 4));
    float* bufA      = (float*)(ws + alloc((size_t)N * HID * 4));
    float* bufB      = (float*)(ws + alloc((size_t)N * HID * 4));
    (void)ws_size; (void)n_in; (void)out_size;

    int nbS = (NSCAN + 1023) / 1024;     // scan blocks for cnts
    int nbN = (N + 1023) / 1024;         // scan blocks for cnt
    int mt  = (N + 63) / 64;

    // ---- binned CSR build ----
    k_binhist<<<NBLK, 256, 0, stream>>>(dstp, E, cnts, NB);
    k_scan1<<<nbS, 256, 0, stream>>>(cnts, NSCAN, bsums);
    k_scan2<<<1, 64, 0, stream>>>(bsums, nbS);
    k_scan3_flat<<<nbS, 256, 0, stream>>>(cnts, NSCAN, bsums);
    k_binscatter<<<NBLK, 256, 0, stream>>>(srcp, dstp, E, cnts, packed, NB);
    k_zero_int<<<(N + 255) / 256, 256, 0, stream>>>(cnt, N);
    k_hist2<<<NB, 256, 0, stream>>>(packed, cnts, E, cnt, NB);
    k_dis<<<(N + 255) / 256, 256, 0, stream>>>(cnt, dis, N);
    k_scan1<<<nbN, 256, 0, stream>>>(cnt, N, bsums);
    k_scan2<<<1, 64, 0, stream>>>(bsums, nbN);
    k_scan3_rows<<<nbN, 256, 0, stream>>>(cnt, N, bsums, row_start, fcur, E);
    k_fill2<<<NB, 256, 0, stream>>>(packed, cnts, E, fcur, csr, NB);

    // ---- network ----
    // low_emb = relu(low @ W_emb + b_emb)            -> bufA
    k_gemm<true, true, false><<<mt, 256, 0, stream>>>(low, LOWD, nullptr, 0, W_emb, b_emb, nullptr, bufA, N);
    // xls1 = ([high | low_emb] @ W1) * dis           -> bufB
    k_gemm<false, false, true><<<mt, 256, 0, stream>>>(high, HIGH, bufA, EMB, W1, nullptr, dis, bufB, N);
    // h1 = relu(dis * (gather(xls1) + self) + b1)    -> bufA
    k_gather<<<(N + 3) / 4, 256, 0, stream>>>(bufB, row_start, csr, dis, b1, bufA, N);
    // xls2 = (h1 @ W2) * dis                         -> bufB
    k_gemm<false, false, true><<<mt, 256, 0, stream>>>(bufA, HID, nullptr, 0, W2, nullptr, dis, bufB, N);
    // h2 = relu(dis * (gather(xls2) + self) + b2)    -> bufA
    k_gather<<<(N + 3) / 4, 256, 0, stream>>>(bufB, row_start, csr, dis, b2, bufA, N);
    // out = log_softmax(h2 @ W_lin + b_lin)
    k_final<<<(N + 3) / 4, 256, 0, stream>>>(bufA, Wl, bl, out, N);
}

// Round 3
// 766.581 us; speedup vs baseline: 1.4610x; 1.2610x over previous
//
#include <hip/hip_runtime.h>

#define HIGH 384
#define LOWD 64
#define EMB  128
#define HID  128

// Binned CSR build: bin = dst >> 8. Requires N <= 131072 (src packs in 17 bits).
#define BINSHIFT 8
#define SRCBITS  17
#define SRCMASK  0x1FFFF
#define NBLK     512

typedef unsigned int u32;

__device__ __forceinline__ float bf_lo(u32 v) { u32 t = v << 16; return __builtin_bit_cast(float, t); }
__device__ __forceinline__ float bf_hi(u32 v) { u32 t = v & 0xffff0000u; return __builtin_bit_cast(float, t); }
__device__ __forceinline__ u32 pack_bf16(float a, float b) {
    u32 ua = __builtin_bit_cast(u32, a);
    u32 ub = __builtin_bit_cast(u32, b);
    ua += 0x7fffu + ((ua >> 16) & 1u);
    ub += 0x7fffu + ((ub >> 16) & 1u);
    return (ua >> 16) | (ub & 0xffff0000u);
}

// ---------------- utility kernels ----------------

__global__ void k_zero_int(int* p, int n) {
    int i = blockIdx.x * 256 + threadIdx.x;
    if (i < n) p[i] = 0;
}

__global__ void k_dis(const int* __restrict__ cnt, float* __restrict__ dis, int N) {
    int i = blockIdx.x * 256 + threadIdx.x;
    if (i < N) dis[i] = rsqrtf((float)cnt[i] + 1.0f);
}

// ---------------- binned edge partition ----------------

__global__ __launch_bounds__(256) void k_binhist(const int* __restrict__ dst, int E,
                                                 int* __restrict__ cnts, int NB) {
    __shared__ int hist[512];
    for (int b = threadIdx.x; b < NB; b += 256) hist[b] = 0;
    __syncthreads();
    int CH = (E + gridDim.x - 1) / gridDim.x;
    int e0 = blockIdx.x * CH;
    int e1 = min(E, e0 + CH);
    for (int e = e0 + threadIdx.x; e < e1; e += 256)
        atomicAdd(&hist[dst[e] >> BINSHIFT], 1);
    __syncthreads();
    for (int b = threadIdx.x; b < NB; b += 256)
        cnts[b * NBLK + blockIdx.x] = hist[b];
}

__global__ __launch_bounds__(256) void k_binscatter(const int* __restrict__ src,
                                                    const int* __restrict__ dst, int E,
                                                    const int* __restrict__ cnts,
                                                    u32* __restrict__ packed, int NB) {
    __shared__ int cur[512];
    for (int b = threadIdx.x; b < NB; b += 256) cur[b] = cnts[b * NBLK + blockIdx.x];
    __syncthreads();
    int CH = (E + gridDim.x - 1) / gridDim.x;
    int e0 = blockIdx.x * CH;
    int e1 = min(E, e0 + CH);
    for (int e = e0 + threadIdx.x; e < e1; e += 256) {
        int d = dst[e];
        int s = src[e];
        int bin = d >> BINSHIFT;
        int pos = atomicAdd(&cur[bin], 1);
        packed[pos] = (u32)s | ((u32)(d & 255) << SRCBITS);
    }
}

__global__ __launch_bounds__(256) void k_hist2(const u32* __restrict__ packed,
                                               const int* __restrict__ cnts, int E,
                                               int* __restrict__ cnt, int NB) {
    int b = blockIdx.x;
    int begin = cnts[b * NBLK];
    int end = (b + 1 < NB) ? cnts[(b + 1) * NBLK] : E;
    int base = b << BINSHIFT;
    for (int e = begin + threadIdx.x; e < end; e += 256) {
        u32 p = packed[e];
        atomicAdd(&cnt[base + (p >> SRCBITS)], 1);
    }
}

__global__ __launch_bounds__(256) void k_fill2(const u32* __restrict__ packed,
                                               const int* __restrict__ cnts, int E,
                                               int* __restrict__ fcur, int* __restrict__ csr,
                                               int NB) {
    int b = blockIdx.x;
    int begin = cnts[b * NBLK];
    int end = (b + 1 < NB) ? cnts[(b + 1) * NBLK] : E;
    int base = b << BINSHIFT;
    for (int e = begin + threadIdx.x; e < end; e += 256) {
        u32 p = packed[e];
        int d = base + (int)(p >> SRCBITS);
        int pos = atomicAdd(&fcur[d], 1);
        csr[pos] = (int)(p & SRCMASK);
    }
}

// ---------------- scan (3-kernel, generic) ----------------

__global__ void k_scan1(const int* __restrict__ in, int n, int* __restrict__ bsums) {
    __shared__ int sh[256];
    int t = threadIdx.x;
    int base = blockIdx.x * 1024 + t * 4;
    int s = 0;
#pragma unroll
    for (int j = 0; j < 4; j++) { int idx = base + j; s += (idx < n) ? in[idx] : 0; }
    sh[t] = s; __syncthreads();
    for (int off = 128; off > 0; off >>= 1) {
        if (t < off) sh[t] += sh[t + off];
        __syncthreads();
    }
    if (t == 0) bsums[blockIdx.x] = sh[0];
}

__global__ void k_scan2(int* bsums, int nb) {
    if (threadIdx.x == 0 && blockIdx.x == 0) {
        int run = 0;
        for (int i = 0; i < nb; i++) { int v = bsums[i]; bsums[i] = run; run += v; }
    }
}

__global__ void k_scan3_flat(int* __restrict__ data, int n, const int* __restrict__ bsums) {
    __shared__ int sh[256];
    int t = threadIdx.x;
    int base = blockIdx.x * 1024 + t * 4;
    int v[4]; int s = 0;
#pragma unroll
    for (int j = 0; j < 4; j++) { int idx = base + j; v[j] = (idx < n) ? data[idx] : 0; s += v[j]; }
    sh[t] = s; __syncthreads();
    int x = s;
    for (int off = 1; off < 256; off <<= 1) {
        int y = (t >= off) ? sh[t - off] : 0;
        __syncthreads();
        x += y; sh[t] = x;
        __syncthreads();
    }
    int run = bsums[blockIdx.x] + (x - s);
#pragma unroll
    for (int j = 0; j < 4; j++) {
        int idx = base + j;
        if (idx < n) data[idx] = run;
        run += v[j];
    }
}

__global__ void k_scan3_rows(const int* __restrict__ cnt, int N, const int* __restrict__ bsums,
                             int* __restrict__ row_start, int* __restrict__ fcur, int E) {
    __shared__ int sh[256];
    int t = threadIdx.x;
    int base = blockIdx.x * 1024 + t * 4;
    int v[4]; int s = 0;
#pragma unroll
    for (int j = 0; j < 4; j++) { int idx = base + j; v[j] = (idx < N) ? cnt[idx] : 0; s += v[j]; }
    sh[t] = s; __syncthreads();
    int x = s;
    for (int off = 1; off < 256; off <<= 1) {
        int y = (t >= off) ? sh[t - off] : 0;
        __syncthreads();
        x += y; sh[t] = x;
        __syncthreads();
    }
    int run = bsums[blockIdx.x] + (x - s);
#pragma unroll
    for (int j = 0; j < 4; j++) {
        int idx = base + j;
        if (idx < N) { row_start[idx] = run; fcur[idx] = run; }
        run += v[j];
    }
    if (blockIdx.x == 0 && t == 0) row_start[N] = E;
}

// ---------------- fused GEMM: C[M x 128] = [A1|A2] @ W  (+bias) (*dis) (relu) ----------------
// OUT_BF16: pack epilogue to bf16 (row = 128 bf16 = 256B).

template<bool BIAS, bool RELU, bool SCALE, bool OUT_BF16>
__global__ __launch_bounds__(256) void k_gemm(
    const float* __restrict__ A1, int K1,
    const float* __restrict__ A2, int K2,
    const float* __restrict__ W,
    const float* __restrict__ bias,
    const float* __restrict__ dis,
    float* __restrict__ C, int M)
{
    __shared__ float As[32][68];
    __shared__ float Ws[32][132];

    const int tid = threadIdx.x;
    const int tx = tid & 15;
    const int ty = tid >> 4;
    const int blockRow = blockIdx.x * 64;
    const int K = K1 + K2;

    float acc[4][8];
#pragma unroll
    for (int i = 0; i < 4; i++)
#pragma unroll
        for (int j = 0; j < 8; j++) acc[i][j] = 0.f;

    const int la_m = tid >> 3;
    const int la_c = (tid & 7) * 4;
    const int lw_j = (tid & 31) * 4;
    const int lw_k = tid >> 5;

    for (int k0 = 0; k0 < K; k0 += 32) {
        const float* A; int lda, kcol;
        if (k0 < K1) { A = A1; lda = K1; kcol = k0; }
        else         { A = A2; lda = K2; kcol = k0 - K1; }

#pragma unroll
        for (int h = 0; h < 2; h++) {
            int m = la_m + h * 32;
            int row = blockRow + m; if (row >= M) row = M - 1;
            const float4 av = *(const float4*)&A[(size_t)row * lda + kcol + la_c];
            As[la_c + 0][m] = av.x; As[la_c + 1][m] = av.y;
            As[la_c + 2][m] = av.z; As[la_c + 3][m] = av.w;
        }
#pragma unroll
        for (int h = 0; h < 4; h++) {
            int kk = lw_k + h * 8;
            const float4 wv = *(const float4*)&W[(size_t)(k0 + kk) * 128 + lw_j];
            *(float4*)&Ws[kk][lw_j] = wv;
        }
        __syncthreads();

#pragma unroll
        for (int kk = 0; kk < 32; kk++) {
            float4 a  = *(const float4*)&As[kk][ty * 4];
            float4 w0 = *(const float4*)&Ws[kk][tx * 8];
            float4 w1 = *(const float4*)&Ws[kk][tx * 8 + 4];
            float av[4] = {a.x, a.y, a.z, a.w};
            float wv[8] = {w0.x, w0.y, w0.z, w0.w, w1.x, w1.y, w1.z, w1.w};
#pragma unroll
            for (int i = 0; i < 4; i++)
#pragma unroll
                for (int j = 0; j < 8; j++)
                    acc[i][j] = fmaf(av[i], wv[j], acc[i][j]);
        }
        __syncthreads();
    }

#pragma unroll
    for (int i = 0; i < 4; i++) {
        int row = blockRow + ty * 4 + i;
        if (row < M) {
            float scale = SCALE ? dis[row] : 1.0f;
            float out[8];
#pragma unroll
            for (int j = 0; j < 8; j++) {
                float v = acc[i][j];
                if (BIAS) v += bias[tx * 8 + j];
                if (SCALE) v *= scale;
                if (RELU) v = fmaxf(v, 0.f);
                out[j] = v;
            }
            if (OUT_BF16) {
                u32* cp = (u32*)C + (size_t)row * 64 + tx * 4;
                cp[0] = pack_bf16(out[0], out[1]);
                cp[1] = pack_bf16(out[2], out[3]);
                cp[2] = pack_bf16(out[4], out[5]);
                cp[3] = pack_bf16(out[6], out[7]);
            } else {
                float4* cp = (float4*)&C[(size_t)row * 128 + tx * 8];
                cp[0] = make_float4(out[0], out[1], out[2], out[3]);
                cp[1] = make_float4(out[4], out[5], out[6], out[7]);
            }
        }
    }
}

// ---------------- gather (bf16 in, fp32 out) ----------------
// h[n] = relu(dis[n] * (sum_{s in N(n)} xls[s] + xls[n]) + b)
// xls rows are 128 bf16 = 256B; lane reads one u32 (2 bf16).

__global__ __launch_bounds__(256) void k_gather(
    const u32* __restrict__ xls, const int* __restrict__ row_start,
    const int* __restrict__ csr, const float* __restrict__ dis,
    const float* __restrict__ bias, float* __restrict__ h, int N)
{
    int wave = threadIdx.x >> 6;
    int lane = threadIdx.x & 63;
    int n = blockIdx.x * 4 + wave;
    if (n >= N) return;
    int jb = row_start[n], je = row_start[n + 1];

    u32 selfv = xls[(size_t)n * 64 + lane];
    float acc0 = bf_lo(selfv), acc1 = bf_hi(selfv);

    int j = jb;
    for (; j + 3 < je; j += 4) {
        int s0 = csr[j], s1 = csr[j + 1], s2 = csr[j + 2], s3 = csr[j + 3];
        u32 v0 = xls[(size_t)s0 * 64 + lane];
        u32 v1 = xls[(size_t)s1 * 64 + lane];
        u32 v2 = xls[(size_t)s2 * 64 + lane];
        u32 v3 = xls[(size_t)s3 * 64 + lane];
        acc0 += bf_lo(v0) + bf_lo(v1) + bf_lo(v2) + bf_lo(v3);
        acc1 += bf_hi(v0) + bf_hi(v1) + bf_hi(v2) + bf_hi(v3);
    }
    for (; j < je; j++) {
        int s = csr[j];
        u32 v = xls[(size_t)s * 64 + lane];
        acc0 += bf_lo(v);
        acc1 += bf_hi(v);
    }
    float d = dis[n];
    float o0 = fmaxf(fmaf(d, acc0, bias[lane * 2 + 0]), 0.f);
    float o1 = fmaxf(fmaf(d, acc1, bias[lane * 2 + 1]), 0.f);
    *(float2*)&h[(size_t)n * 128 + lane * 2] = make_float2(o0, o1);
}

// ---------------- final: logits + log_softmax ----------------

__global__ __launch_bounds__(256) void k_final(
    const float* __restrict__ h, const float* __restrict__ Wl,
    const float* __restrict__ bl, float* __restrict__ out, int N)
{
    int wave = threadIdx.x >> 6, lane = threadIdx.x & 63;
    int n = blockIdx.x * 4 + wave;
    if (n >= N) return;
    float h0 = h[(size_t)n * 128 + lane];
    float h1 = h[(size_t)n * 128 + lane + 64];
    float p0 = h0 * Wl[lane * 2 + 0] + h1 * Wl[(lane + 64) * 2 + 0];
    float p1 = h0 * Wl[lane * 2 + 1] + h1 * Wl[(lane + 64) * 2 + 1];
#pragma unroll
    for (int off = 32; off > 0; off >>= 1) {
        p0 += __shfl_down(p0, off);
        p1 += __shfl_down(p1, off);
    }
    if (lane == 0) {
        float z0 = p0 + bl[0], z1 = p1 + bl[1];
        float m = fmaxf(z0, z1);
        float ls = m + logf(expf(z0 - m) + expf(z1 - m));
        out[(size_t)n * 2 + 0] = z0 - ls;
        out[(size_t)n * 2 + 1] = z1 - ls;
    }
}

// ---------------- launch ----------------

extern "C" void kernel_launch(void* const* d_in, const int* in_sizes, int n_in,
                              void* d_out, int out_size, void* d_ws, size_t ws_size,
                              hipStream_t stream) {
    const float* high  = (const float*)d_in[0];
    const float* low   = (const float*)d_in[1];
    const int*   ei    = (const int*)d_in[2];
    const float* W_emb = (const float*)d_in[3];
    const float* b_emb = (const float*)d_in[4];
    const float* W1    = (const float*)d_in[5];
    const float* b1    = (const float*)d_in[6];
    const float* W2    = (const float*)d_in[7];
    const float* b2    = (const float*)d_in[8];
    const float* Wl    = (const float*)d_in[9];
    const float* bl    = (const float*)d_in[10];

    int N = in_sizes[0] / HIGH;
    int E = in_sizes[2] / 2;
    const int* srcp = ei;
    const int* dstp = ei + E;
    float* out = (float*)d_out;

    int NB = (N + 255) >> BINSHIFT;
    int NSCAN = NB * NBLK;

    char* ws = (char*)d_ws;
    size_t off = 0;
    auto alloc = [&](size_t b) { size_t o = off; off += (b + 255) & ~(size_t)255; return o; };
    float* dis       = (float*)(ws + alloc((size_t)N * 4));
    int*   cnt       = (int*)  (ws + alloc((size_t)N * 4));
    int*   row_start = (int*)  (ws + alloc((size_t)(N + 1) * 4));
    int*   fcur      = (int*)  (ws + alloc((size_t)N * 4));
    int*   bsums     = (int*)  (ws + alloc(4096));
    int*   cnts      = (int*)  (ws + alloc((size_t)NSCAN * 4));
    u32*   packed    = (u32*)  (ws + alloc((size_t)E * 4));
    int*   csr       = (int*)  (ws + alloc((size_t)E * 4));
    float* bufA      = (float*)(ws + alloc((size_t)N * HID * 4));   // fp32 (emb out, gather out)
    float* bufB      = (float*)(ws + alloc((size_t)N * HID * 4));   // bf16 xls lives here
    (void)ws_size; (void)n_in; (void)out_size;

    int nbS = (NSCAN + 1023) / 1024;
    int nbN = (N + 1023) / 1024;
    int mt  = (N + 63) / 64;

    // ---- binned CSR build ----
    k_binhist<<<NBLK, 256, 0, stream>>>(dstp, E, cnts, NB);
    k_scan1<<<nbS, 256, 0, stream>>>(cnts, NSCAN, bsums);
    k_scan2<<<1, 64, 0, stream>>>(bsums, nbS);
    k_scan3_flat<<<nbS, 256, 0, stream>>>(cnts, NSCAN, bsums);
    k_binscatter<<<NBLK, 256, 0, stream>>>(srcp, dstp, E, cnts, packed, NB);
    k_zero_int<<<(N + 255) / 256, 256, 0, stream>>>(cnt, N);
    k_hist2<<<NB, 256, 0, stream>>>(packed, cnts, E, cnt, NB);
    k_dis<<<(N + 255) / 256, 256, 0, stream>>>(cnt, dis, N);
    k_scan1<<<nbN, 256, 0, stream>>>(cnt, N, bsums);
    k_scan2<<<1, 64, 0, stream>>>(bsums, nbN);
    k_scan3_rows<<<nbN, 256, 0, stream>>>(cnt, N, bsums, row_start, fcur, E);
    k_fill2<<<NB, 256, 0, stream>>>(packed, cnts, E, fcur, csr, NB);

    // ---- network ----
    // low_emb = relu(low @ W_emb + b_emb)                 -> bufA (fp32)
    k_gemm<true, true, false, false><<<mt, 256, 0, stream>>>(low, LOWD, nullptr, 0, W_emb, b_emb, nullptr, bufA, N);
    // xls1 = ([high | low_emb] @ W1) * dis                -> bufB (bf16)
    k_gemm<false, false, true, true><<<mt, 256, 0, stream>>>(high, HIGH, bufA, EMB, W1, nullptr, dis, bufB, N);
    // h1 = relu(dis * (gather(xls1) + self) + b1)         -> bufA (fp32)
    k_gather<<<(N + 3) / 4, 256, 0, stream>>>((const u32*)bufB, row_start, csr, dis, b1, bufA, N);
    // xls2 = (h1 @ W2) * dis                              -> bufB (bf16)
    k_gemm<false, false, true, true><<<mt, 256, 0, stream>>>(bufA, HID, nullptr, 0, W2, nullptr, dis, bufB, N);
    // h2 = relu(dis * (gather(xls2) + self) + b2)         -> bufA (fp32)
    k_gather<<<(N + 3) / 4, 256, 0, stream>>>((const u32*)bufB, row_start, csr, dis, b2, bufA, N);
    // out = log_softmax(h2 @ W_lin + b_lin)
    k_final<<<(N + 3) / 4, 256, 0, stream>>>(bufA, Wl, bl, out, N);
}

// Round 4
// 618.136 us; speedup vs baseline: 1.8119x; 1.2401x over previous
//
#include <hip/hip_runtime.h>

#define HIGH 384
#define LOWD 64
#define EMB  128
#define HID  128

// Binned CSR build: bin = dst >> 8. Requires N <= 131072 (src packs in 17 bits).
#define BINSHIFT 8
#define SRCBITS  17
#define SRCMASK  0x1FFFF
#define NBLK     512

typedef unsigned int u32;
typedef unsigned short u16;
typedef __attribute__((ext_vector_type(8))) short bf16x8;
typedef __attribute__((ext_vector_type(4))) float f32x4;

__device__ __forceinline__ float bf_lo(u32 v) { u32 t = v << 16; return __builtin_bit_cast(float, t); }
__device__ __forceinline__ float bf_hi(u32 v) { u32 t = v & 0xffff0000u; return __builtin_bit_cast(float, t); }
__device__ __forceinline__ u32 pack_bf16(float a, float b) {
    u32 ua = __builtin_bit_cast(u32, a);
    u32 ub = __builtin_bit_cast(u32, b);
    ua += 0x7fffu + ((ua >> 16) & 1u);
    ub += 0x7fffu + ((ub >> 16) & 1u);
    return (ua >> 16) | (ub & 0xffff0000u);
}
__device__ __forceinline__ u16 pack1_bf16(float a) {
    u32 ua = __builtin_bit_cast(u32, a);
    ua += 0x7fffu + ((ua >> 16) & 1u);
    return (u16)(ua >> 16);
}

// ---------------- utility kernels ----------------

__global__ void k_zero_int(int* p, int n) {
    int i = blockIdx.x * 256 + threadIdx.x;
    if (i < n) p[i] = 0;
}

__global__ void k_dis(const int* __restrict__ cnt, float* __restrict__ dis, int N) {
    int i = blockIdx.x * 256 + threadIdx.x;
    if (i < N) dis[i] = rsqrtf((float)cnt[i] + 1.0f);
}

// W[K][128] fp32 -> Wt[128][K] bf16
__global__ void k_castw(const float* __restrict__ W, u16* __restrict__ Wt, int K) {
    int i = blockIdx.x * 256 + threadIdx.x;
    if (i < K * 128) {
        int k = i >> 7, c = i & 127;
        Wt[c * K + k] = pack1_bf16(W[i]);
    }
}

// ---------------- binned edge partition ----------------

__global__ __launch_bounds__(256) void k_binhist(const int* __restrict__ dst, int E,
                                                 int* __restrict__ cnts, int NB) {
    __shared__ int hist[512];
    for (int b = threadIdx.x; b < NB; b += 256) hist[b] = 0;
    __syncthreads();
    int CH = (E + gridDim.x - 1) / gridDim.x;
    int e0 = blockIdx.x * CH;
    int e1 = min(E, e0 + CH);
    for (int e = e0 + threadIdx.x; e < e1; e += 256)
        atomicAdd(&hist[dst[e] >> BINSHIFT], 1);
    __syncthreads();
    for (int b = threadIdx.x; b < NB; b += 256)
        cnts[b * NBLK + blockIdx.x] = hist[b];
}

__global__ __launch_bounds__(256) void k_binscatter(const int* __restrict__ src,
                                                    const int* __restrict__ dst, int E,
                                                    const int* __restrict__ cnts,
                                                    u32* __restrict__ packed, int NB) {
    __shared__ int cur[512];
    for (int b = threadIdx.x; b < NB; b += 256) cur[b] = cnts[b * NBLK + blockIdx.x];
    __syncthreads();
    int CH = (E + gridDim.x - 1) / gridDim.x;
    int e0 = blockIdx.x * CH;
    int e1 = min(E, e0 + CH);
    for (int e = e0 + threadIdx.x; e < e1; e += 256) {
        int d = dst[e];
        int s = src[e];
        int bin = d >> BINSHIFT;
        int pos = atomicAdd(&cur[bin], 1);
        packed[pos] = (u32)s | ((u32)(d & 255) << SRCBITS);
    }
}

__global__ __launch_bounds__(256) void k_hist2(const u32* __restrict__ packed,
                                               const int* __restrict__ cnts, int E,
                                               int* __restrict__ cnt, int NB) {
    int b = blockIdx.x;
    int begin = cnts[b * NBLK];
    int end = (b + 1 < NB) ? cnts[(b + 1) * NBLK] : E;
    int base = b << BINSHIFT;
    for (int e = begin + threadIdx.x; e < end; e += 256) {
        u32 p = packed[e];
        atomicAdd(&cnt[base + (p >> SRCBITS)], 1);
    }
}

__global__ __launch_bounds__(256) void k_fill2(const u32* __restrict__ packed,
                                               const int* __restrict__ cnts, int E,
                                               int* __restrict__ fcur, int* __restrict__ csr,
                                               int NB) {
    int b = blockIdx.x;
    int begin = cnts[b * NBLK];
    int end = (b + 1 < NB) ? cnts[(b + 1) * NBLK] : E;
    int base = b << BINSHIFT;
    for (int e = begin + threadIdx.x; e < end; e += 256) {
        u32 p = packed[e];
        int d = base + (int)(p >> SRCBITS);
        int pos = atomicAdd(&fcur[d], 1);
        csr[pos] = (int)(p & SRCMASK);
    }
}

// ---------------- scan (3-kernel, generic) ----------------

__global__ void k_scan1(const int* __restrict__ in, int n, int* __restrict__ bsums) {
    __shared__ int sh[256];
    int t = threadIdx.x;
    int base = blockIdx.x * 1024 + t * 4;
    int s = 0;
#pragma unroll
    for (int j = 0; j < 4; j++) { int idx = base + j; s += (idx < n) ? in[idx] : 0; }
    sh[t] = s; __syncthreads();
    for (int off = 128; off > 0; off >>= 1) {
        if (t < off) sh[t] += sh[t + off];
        __syncthreads();
    }
    if (t == 0) bsums[blockIdx.x] = sh[0];
}

__global__ void k_scan2(int* bsums, int nb) {
    if (threadIdx.x == 0 && blockIdx.x == 0) {
        int run = 0;
        for (int i = 0; i < nb; i++) { int v = bsums[i]; bsums[i] = run; run += v; }
    }
}

__global__ void k_scan3_flat(int* __restrict__ data, int n, const int* __restrict__ bsums) {
    __shared__ int sh[256];
    int t = threadIdx.x;
    int base = blockIdx.x * 1024 + t * 4;
    int v[4]; int s = 0;
#pragma unroll
    for (int j = 0; j < 4; j++) { int idx = base + j; v[j] = (idx < n) ? data[idx] : 0; s += v[j]; }
    sh[t] = s; __syncthreads();
    int x = s;
    for (int off = 1; off < 256; off <<= 1) {
        int y = (t >= off) ? sh[t - off] : 0;
        __syncthreads();
        x += y; sh[t] = x;
        __syncthreads();
    }
    int run = bsums[blockIdx.x] + (x - s);
#pragma unroll
    for (int j = 0; j < 4; j++) {
        int idx = base + j;
        if (idx < n) data[idx] = run;
        run += v[j];
    }
}

__global__ void k_scan3_rows(const int* __restrict__ cnt, int N, const int* __restrict__ bsums,
                             int* __restrict__ row_start, int* __restrict__ fcur, int E) {
    __shared__ int sh[256];
    int t = threadIdx.x;
    int base = blockIdx.x * 1024 + t * 4;
    int v[4]; int s = 0;
#pragma unroll
    for (int j = 0; j < 4; j++) { int idx = base + j; v[j] = (idx < N) ? cnt[idx] : 0; s += v[j]; }
    sh[t] = s; __syncthreads();
    int x = s;
    for (int off = 1; off < 256; off <<= 1) {
        int y = (t >= off) ? sh[t - off] : 0;
        __syncthreads();
        x += y; sh[t] = x;
        __syncthreads();
    }
    int run = bsums[blockIdx.x] + (x - s);
#pragma unroll
    for (int j = 0; j < 4; j++) {
        int idx = base + j;
        if (idx < N) { row_start[idx] = run; fcur[idx] = run; }
        run += v[j];
    }
    if (blockIdx.x == 0 && t == 0) row_start[N] = E;
}

// ---------------- MFMA GEMM: C[M x 128] = [A1|A2] @ W  (+bias) (*dis) (relu), bf16 out ----
// BM=128, BN=128, BK=32, 256 threads (4 waves), wave tile 32x128 (2x8 frags 16x16x32).
// LDS: [row][16 u32] bf16 pairs, 16B-block XOR swizzle blk ^= ... (+ (row>>1))&3.
// Wt is pre-transposed bf16 [128][K].

template<bool A1BF, bool BIAS, bool RELU, bool SCALE>
__global__ __launch_bounds__(256) void k_mgemm(
    const void* __restrict__ A1v, int K1,
    const u32* __restrict__ A2, int K2,
    const u16* __restrict__ Wt,
    const float* __restrict__ bias,
    const float* __restrict__ dis,
    u16* __restrict__ C, int M)
{
    __shared__ u32 Al[128][16];
    __shared__ u32 Bl[128][16];

    const int tid = threadIdx.x;
    const int l = tid & 63;
    const int w = tid >> 6;
    const int g = l >> 4;      // k-group 0..3
    const int lr = l & 15;
    const int blockRow = blockIdx.x * 128;
    const int K = K1 + K2;

    // staging coords
    const int sr = tid >> 1;       // 0..127 (row for A, col for Wt)
    const int sh_ = tid & 1;       // half: k-offset sh_*16
    int arow = blockRow + sr; if (arow >= M) arow = M - 1;

    f32x4 acc[2][8];
#pragma unroll
    for (int i = 0; i < 2; i++)
#pragma unroll
        for (int j = 0; j < 8; j++) acc[i][j] = (f32x4)0.f;

    const int ssw = (sr >> 1) & 3;          // staging swizzle key
    const u32* wt32 = (const u32*)Wt;

    for (int k0 = 0; k0 < K; k0 += 32) {
        // ---- stage A (fp32->bf16 or bf16 copy) ----
        u32 pk[8];
        if (k0 < K1) {
            if (A1BF) {
                const u32* src = (const u32*)A1v + (size_t)arow * (K1 >> 1) + ((k0 + sh_ * 16) >> 1);
                uint4 a = *(const uint4*)src;
                uint4 b = *(const uint4*)(src + 4);
                pk[0] = a.x; pk[1] = a.y; pk[2] = a.z; pk[3] = a.w;
                pk[4] = b.x; pk[5] = b.y; pk[6] = b.z; pk[7] = b.w;
            } else {
                const float* src = (const float*)A1v + (size_t)arow * K1 + k0 + sh_ * 16;
                float4 f0 = *(const float4*)(src + 0);
                float4 f1 = *(const float4*)(src + 4);
                float4 f2 = *(const float4*)(src + 8);
                float4 f3 = *(const float4*)(src + 12);
                pk[0] = pack_bf16(f0.x, f0.y); pk[1] = pack_bf16(f0.z, f0.w);
                pk[2] = pack_bf16(f1.x, f1.y); pk[3] = pack_bf16(f1.z, f1.w);
                pk[4] = pack_bf16(f2.x, f2.y); pk[5] = pack_bf16(f2.z, f2.w);
                pk[6] = pack_bf16(f3.x, f3.y); pk[7] = pack_bf16(f3.z, f3.w);
            }
        } else {
            const u32* src = A2 + (size_t)arow * (K2 >> 1) + ((k0 - K1 + sh_ * 16) >> 1);
            uint4 a = *(const uint4*)src;
            uint4 b = *(const uint4*)(src + 4);
            pk[0] = a.x; pk[1] = a.y; pk[2] = a.z; pk[3] = a.w;
            pk[4] = b.x; pk[5] = b.y; pk[6] = b.z; pk[7] = b.w;
        }
        {
            int b0 = (sh_ * 2 + ssw) & 3;
            int b1 = (sh_ * 2 + 1 + ssw) & 3;
            *(uint4*)&Al[sr][b0 * 4] = make_uint4(pk[0], pk[1], pk[2], pk[3]);
            *(uint4*)&Al[sr][b1 * 4] = make_uint4(pk[4], pk[5], pk[6], pk[7]);
        }
        // ---- stage Wt (bf16 copy; col = sr) ----
        {
            const u32* src = wt32 + (size_t)sr * (K >> 1) + ((k0 + sh_ * 16) >> 1);
            uint4 a = *(const uint4*)src;
            uint4 b = *(const uint4*)(src + 4);
            int b0 = (sh_ * 2 + ssw) & 3;
            int b1 = (sh_ * 2 + 1 + ssw) & 3;
            *(uint4*)&Bl[sr][b0 * 4] = a;
            *(uint4*)&Bl[sr][b1 * 4] = b;
        }
        __syncthreads();

        // ---- compute ----
        bf16x8 af[2];
#pragma unroll
        for (int rf = 0; rf < 2; rf++) {
            int r = w * 32 + rf * 16 + lr;
            int blk = (g + ((r >> 1) & 3)) & 3;
            af[rf] = *(const bf16x8*)&Al[r][blk * 4];
        }
#pragma unroll
        for (int cb = 0; cb < 8; cb++) {
            int c = cb * 16 + lr;
            int blk = (g + ((c >> 1) & 3)) & 3;
            bf16x8 bf = *(const bf16x8*)&Bl[c][blk * 4];
            acc[0][cb] = __builtin_amdgcn_mfma_f32_16x16x32_bf16(af[0], bf, acc[0][cb], 0, 0, 0);
            acc[1][cb] = __builtin_amdgcn_mfma_f32_16x16x32_bf16(af[1], bf, acc[1][cb], 0, 0, 0);
        }
        __syncthreads();
    }

    // ---- epilogue ----
    float disv[2][4];
    if (SCALE) {
#pragma unroll
        for (int rf = 0; rf < 2; rf++)
#pragma unroll
            for (int j = 0; j < 4; j++) {
                int row = blockRow + w * 32 + rf * 16 + g * 4 + j;
                disv[rf][j] = (row < M) ? dis[row] : 0.f;
            }
    }
#pragma unroll
    for (int rf = 0; rf < 2; rf++) {
#pragma unroll
        for (int cb = 0; cb < 8; cb++) {
            int col = cb * 16 + lr;
            float bv = BIAS ? bias[col] : 0.f;
#pragma unroll
            for (int j = 0; j < 4; j++) {
                int row = blockRow + w * 32 + rf * 16 + g * 4 + j;
                if (row < M) {
                    float v = acc[rf][cb][j];
                    if (BIAS) v += bv;
                    if (SCALE) v *= disv[rf][j];
                    if (RELU) v = fmaxf(v, 0.f);
                    C[(size_t)row * 128 + col] = pack1_bf16(v);
                }
            }
        }
    }
}

// ---------------- gather (bf16 in, fp32 or bf16 out) ----------------
// h[n] = relu(dis[n] * (sum_{s in N(n)} xls[s] + xls[n]) + b)

template<bool OUTBF>
__global__ __launch_bounds__(256) void k_gather(
    const u32* __restrict__ xls, const int* __restrict__ row_start,
    const int* __restrict__ csr, const float* __restrict__ dis,
    const float* __restrict__ bias, void* __restrict__ hv, int N)
{
    int wave = threadIdx.x >> 6;
    int lane = threadIdx.x & 63;
    int n = blockIdx.x * 4 + wave;
    if (n >= N) return;
    int jb = row_start[n], je = row_start[n + 1];

    u32 selfv = xls[(size_t)n * 64 + lane];
    float acc0 = bf_lo(selfv), acc1 = bf_hi(selfv);

    int j = jb;
    for (; j + 3 < je; j += 4) {
        int s0 = csr[j], s1 = csr[j + 1], s2 = csr[j + 2], s3 = csr[j + 3];
        u32 v0 = xls[(size_t)s0 * 64 + lane];
        u32 v1 = xls[(size_t)s1 * 64 + lane];
        u32 v2 = xls[(size_t)s2 * 64 + lane];
        u32 v3 = xls[(size_t)s3 * 64 + lane];
        acc0 += bf_lo(v0) + bf_lo(v1) + bf_lo(v2) + bf_lo(v3);
        acc1 += bf_hi(v0) + bf_hi(v1) + bf_hi(v2) + bf_hi(v3);
    }
    for (; j < je; j++) {
        int s = csr[j];
        u32 v = xls[(size_t)s * 64 + lane];
        acc0 += bf_lo(v);
        acc1 += bf_hi(v);
    }
    float d = dis[n];
    float o0 = fmaxf(fmaf(d, acc0, bias[lane * 2 + 0]), 0.f);
    float o1 = fmaxf(fmaf(d, acc1, bias[lane * 2 + 1]), 0.f);
    if (OUTBF) {
        ((u32*)hv)[(size_t)n * 64 + lane] = pack_bf16(o0, o1);
    } else {
        *(float2*)&((float*)hv)[(size_t)n * 128 + lane * 2] = make_float2(o0, o1);
    }
}

// ---------------- final: logits + log_softmax ----------------

__global__ __launch_bounds__(256) void k_final(
    const float* __restrict__ h, const float* __restrict__ Wl,
    const float* __restrict__ bl, float* __restrict__ out, int N)
{
    int wave = threadIdx.x >> 6, lane = threadIdx.x & 63;
    int n = blockIdx.x * 4 + wave;
    if (n >= N) return;
    float h0 = h[(size_t)n * 128 + lane];
    float h1 = h[(size_t)n * 128 + lane + 64];
    float p0 = h0 * Wl[lane * 2 + 0] + h1 * Wl[(lane + 64) * 2 + 0];
    float p1 = h0 * Wl[lane * 2 + 1] + h1 * Wl[(lane + 64) * 2 + 1];
#pragma unroll
    for (int off = 32; off > 0; off >>= 1) {
        p0 += __shfl_down(p0, off);
        p1 += __shfl_down(p1, off);
    }
    if (lane == 0) {
        float z0 = p0 + bl[0], z1 = p1 + bl[1];
        float m = fmaxf(z0, z1);
        float ls = m + logf(expf(z0 - m) + expf(z1 - m));
        out[(size_t)n * 2 + 0] = z0 - ls;
        out[(size_t)n * 2 + 1] = z1 - ls;
    }
}

// ---------------- launch ----------------

extern "C" void kernel_launch(void* const* d_in, const int* in_sizes, int n_in,
                              void* d_out, int out_size, void* d_ws, size_t ws_size,
                              hipStream_t stream) {
    const float* high  = (const float*)d_in[0];
    const float* low   = (const float*)d_in[1];
    const int*   ei    = (const int*)d_in[2];
    const float* W_emb = (const float*)d_in[3];
    const float* b_emb = (const float*)d_in[4];
    const float* W1    = (const float*)d_in[5];
    const float* b1    = (const float*)d_in[6];
    const float* W2    = (const float*)d_in[7];
    const float* b2    = (const float*)d_in[8];
    const float* Wl    = (const float*)d_in[9];
    const float* bl    = (const float*)d_in[10];

    int N = in_sizes[0] / HIGH;
    int E = in_sizes[2] / 2;
    const int* srcp = ei;
    const int* dstp = ei + E;
    float* out = (float*)d_out;

    int NB = (N + 255) >> BINSHIFT;
    int NSCAN = NB * NBLK;

    char* ws = (char*)d_ws;
    size_t off = 0;
    auto alloc = [&](size_t b) { size_t o = off; off += (b + 255) & ~(size_t)255; return o; };
    float* dis       = (float*)(ws + alloc((size_t)N * 4));
    int*   cnt       = (int*)  (ws + alloc((size_t)N * 4));
    int*   row_start = (int*)  (ws + alloc((size_t)(N + 1) * 4));
    int*   fcur      = (int*)  (ws + alloc((size_t)N * 4));
    int*   bsums     = (int*)  (ws + alloc(4096));
    int*   cnts      = (int*)  (ws + alloc((size_t)NSCAN * 4));
    u32*   packed    = (u32*)  (ws + alloc((size_t)E * 4));
    int*   csr       = (int*)  (ws + alloc((size_t)E * 4));
    u16*   Wt1       = (u16*)  (ws + alloc((size_t)512 * 128 * 2));
    u16*   Wt2       = (u16*)  (ws + alloc((size_t)128 * 128 * 2));
    u16*   WtE       = (u16*)  (ws + alloc((size_t)64 * 128 * 2));
    char*  bufE      = (char*) (ws + alloc((size_t)N * 128 * 4));  // bf16 low_emb, later fp32 h2
    u16*   bufX      = (u16*)  (ws + alloc((size_t)N * 128 * 2));  // bf16 xls
    u16*   bufH      = (u16*)  (ws + alloc((size_t)N * 128 * 2));  // bf16 h1
    (void)ws_size; (void)n_in; (void)out_size;

    int nbS = (NSCAN + 1023) / 1024;
    int nbN = (N + 1023) / 1024;
    int mt  = (N + 127) / 128;

    // ---- weight transpose+cast (tiny) ----
    k_castw<<<(512 * 128 + 255) / 256, 256, 0, stream>>>(W1, Wt1, 512);
    k_castw<<<(128 * 128 + 255) / 256, 256, 0, stream>>>(W2, Wt2, 128);
    k_castw<<<(64 * 128 + 255) / 256, 256, 0, stream>>>(W_emb, WtE, 64);

    // ---- binned CSR build ----
    k_binhist<<<NBLK, 256, 0, stream>>>(dstp, E, cnts, NB);
    k_scan1<<<nbS, 256, 0, stream>>>(cnts, NSCAN, bsums);
    k_scan2<<<1, 64, 0, stream>>>(bsums, nbS);
    k_scan3_flat<<<nbS, 256, 0, stream>>>(cnts, NSCAN, bsums);
    k_binscatter<<<NBLK, 256, 0, stream>>>(srcp, dstp, E, cnts, packed, NB);
    k_zero_int<<<(N + 255) / 256, 256, 0, stream>>>(cnt, N);
    k_hist2<<<NB, 256, 0, stream>>>(packed, cnts, E, cnt, NB);
    k_dis<<<(N + 255) / 256, 256, 0, stream>>>(cnt, dis, N);
    k_scan1<<<nbN, 256, 0, stream>>>(cnt, N, bsums);
    k_scan2<<<1, 64, 0, stream>>>(bsums, nbN);
    k_scan3_rows<<<nbN, 256, 0, stream>>>(cnt, N, bsums, row_start, fcur, E);
    k_fill2<<<NB, 256, 0, stream>>>(packed, cnts, E, fcur, csr, NB);

    // ---- network ----
    // low_emb = relu(low @ W_emb + b_emb)                 -> bufE (bf16)
    k_mgemm<false, true, true, false><<<mt, 256, 0, stream>>>(
        low, LOWD, nullptr, 0, WtE, b_emb, nullptr, (u16*)bufE, N);
    // xls1 = ([high | low_emb] @ W1) * dis                -> bufX (bf16)
    k_mgemm<false, false, false, true><<<mt, 256, 0, stream>>>(
        high, HIGH, (const u32*)bufE, EMB, Wt1, nullptr, dis, bufX, N);
    // h1 = relu(dis * (gather(xls1) + self) + b1)         -> bufH (bf16)
    k_gather<true><<<(N + 3) / 4, 256, 0, stream>>>(
        (const u32*)bufX, row_start, csr, dis, b1, bufH, N);
    // xls2 = (h1 @ W2) * dis                              -> bufX (bf16)
    k_mgemm<true, false, false, true><<<mt, 256, 0, stream>>>(
        bufH, HID, nullptr, 0, Wt2, nullptr, dis, bufX, N);
    // h2 = relu(dis * (gather(xls2) + self) + b2)         -> bufE (fp32)
    k_gather<false><<<(N + 3) / 4, 256, 0, stream>>>(
        (const u32*)bufX, row_start, csr, dis, b2, bufE, N);
    // out = log_softmax(h2 @ W_lin + b_lin)
    k_final<<<(N + 3) / 4, 256, 0, stream>>>((const float*)bufE, Wl, bl, out, N);
}

// Round 5
// 565.040 us; speedup vs baseline: 1.9822x; 1.0940x over previous
//
#include <hip/hip_runtime.h>

#define HIGH 384
#define LOWD 64
#define EMB  128
#define HID  128

// Binned CSR build: bin = dst >> 8. Requires N <= 131072 (src packs in 17 bits).
#define BINSHIFT 8
#define SRCBITS  17
#define SRCMASK  0x1FFFF
#define NBLK     512

typedef unsigned int u32;
typedef unsigned short u16;
typedef unsigned char u8;
typedef __attribute__((ext_vector_type(8))) short bf16x8;
typedef __attribute__((ext_vector_type(4))) float f32x4;
typedef __attribute__((ext_vector_type(2))) float f32x2;

__device__ __forceinline__ u32 pack_bf16(float a, float b) {
    u32 ua = __builtin_bit_cast(u32, a);
    u32 ub = __builtin_bit_cast(u32, b);
    ua += 0x7fffu + ((ua >> 16) & 1u);
    ub += 0x7fffu + ((ub >> 16) & 1u);
    return (ua >> 16) | (ub & 0xffff0000u);
}
__device__ __forceinline__ u16 pack1_bf16(float a) {
    u32 ua = __builtin_bit_cast(u32, a);
    ua += 0x7fffu + ((ua >> 16) & 1u);
    return (u16)(ua >> 16);
}
__device__ __forceinline__ u8 pack1_fp8(float a) {
    int r = __builtin_amdgcn_cvt_pk_fp8_f32(a, a, 0, false);
    return (u8)(r & 0xff);
}

// ---------------- utility kernels ----------------

__global__ void k_zero_int(int* p, int n) {
    int i = blockIdx.x * 256 + threadIdx.x;
    if (i < n) p[i] = 0;
}

__global__ void k_dis(const int* __restrict__ cnt, float* __restrict__ dis, int N) {
    int i = blockIdx.x * 256 + threadIdx.x;
    if (i < N) dis[i] = rsqrtf((float)cnt[i] + 1.0f);
}

// W[K][128] fp32 -> Wt[128][K] bf16
__global__ void k_castw(const float* __restrict__ W, u16* __restrict__ Wt, int K) {
    int i = blockIdx.x * 256 + threadIdx.x;
    if (i < K * 128) {
        int k = i >> 7, c = i & 127;
        Wt[c * K + k] = pack1_bf16(W[i]);
    }
}

// ---------------- binned edge partition ----------------

__global__ __launch_bounds__(256) void k_binhist(const int* __restrict__ dst, int E,
                                                 int* __restrict__ cnts, int NB) {
    __shared__ int hist[512];
    for (int b = threadIdx.x; b < NB; b += 256) hist[b] = 0;
    __syncthreads();
    int CH = (E + gridDim.x - 1) / gridDim.x;
    int e0 = blockIdx.x * CH;
    int e1 = min(E, e0 + CH);
    for (int e = e0 + threadIdx.x; e < e1; e += 256)
        atomicAdd(&hist[dst[e] >> BINSHIFT], 1);
    __syncthreads();
    for (int b = threadIdx.x; b < NB; b += 256)
        cnts[b * NBLK + blockIdx.x] = hist[b];
}

__global__ __launch_bounds__(256) void k_binscatter(const int* __restrict__ src,
                                                    const int* __restrict__ dst, int E,
                                                    const int* __restrict__ cnts,
                                                    u32* __restrict__ packed, int NB) {
    __shared__ int cur[512];
    for (int b = threadIdx.x; b < NB; b += 256) cur[b] = cnts[b * NBLK + blockIdx.x];
    __syncthreads();
    int CH = (E + gridDim.x - 1) / gridDim.x;
    int e0 = blockIdx.x * CH;
    int e1 = min(E, e0 + CH);
    for (int e = e0 + threadIdx.x; e < e1; e += 256) {
        int d = dst[e];
        int s = src[e];
        int bin = d >> BINSHIFT;
        int pos = atomicAdd(&cur[bin], 1);
        packed[pos] = (u32)s | ((u32)(d & 255) << SRCBITS);
    }
}

__global__ __launch_bounds__(256) void k_hist2(const u32* __restrict__ packed,
                                               const int* __restrict__ cnts, int E,
                                               int* __restrict__ cnt, int NB) {
    int b = blockIdx.x;
    int begin = cnts[b * NBLK];
    int end = (b + 1 < NB) ? cnts[(b + 1) * NBLK] : E;
    int base = b << BINSHIFT;
    for (int e = begin + threadIdx.x; e < end; e += 256) {
        u32 p = packed[e];
        atomicAdd(&cnt[base + (p >> SRCBITS)], 1);
    }
}

__global__ __launch_bounds__(256) void k_fill2(const u32* __restrict__ packed,
                                               const int* __restrict__ cnts, int E,
                                               int* __restrict__ fcur, int* __restrict__ csr,
                                               int NB) {
    int b = blockIdx.x;
    int begin = cnts[b * NBLK];
    int end = (b + 1 < NB) ? cnts[(b + 1) * NBLK] : E;
    int base = b << BINSHIFT;
    for (int e = begin + threadIdx.x; e < end; e += 256) {
        u32 p = packed[e];
        int d = base + (int)(p >> SRCBITS);
        int pos = atomicAdd(&fcur[d], 1);
        csr[pos] = (int)(p & SRCMASK);
    }
}

// ---------------- scan (3-kernel, generic) ----------------

__global__ void k_scan1(const int* __restrict__ in, int n, int* __restrict__ bsums) {
    __shared__ int sh[256];
    int t = threadIdx.x;
    int base = blockIdx.x * 1024 + t * 4;
    int s = 0;
#pragma unroll
    for (int j = 0; j < 4; j++) { int idx = base + j; s += (idx < n) ? in[idx] : 0; }
    sh[t] = s; __syncthreads();
    for (int off = 128; off > 0; off >>= 1) {
        if (t < off) sh[t] += sh[t + off];
        __syncthreads();
    }
    if (t == 0) bsums[blockIdx.x] = sh[0];
}

__global__ void k_scan2(int* bsums, int nb) {
    if (threadIdx.x == 0 && blockIdx.x == 0) {
        int run = 0;
        for (int i = 0; i < nb; i++) { int v = bsums[i]; bsums[i] = run; run += v; }
    }
}

__global__ void k_scan3_flat(int* __restrict__ data, int n, const int* __restrict__ bsums) {
    __shared__ int sh[256];
    int t = threadIdx.x;
    int base = blockIdx.x * 1024 + t * 4;
    int v[4]; int s = 0;
#pragma unroll
    for (int j = 0; j < 4; j++) { int idx = base + j; v[j] = (idx < n) ? data[idx] : 0; s += v[j]; }
    sh[t] = s; __syncthreads();
    int x = s;
    for (int off = 1; off < 256; off <<= 1) {
        int y = (t >= off) ? sh[t - off] : 0;
        __syncthreads();
        x += y; sh[t] = x;
        __syncthreads();
    }
    int run = bsums[blockIdx.x] + (x - s);
#pragma unroll
    for (int j = 0; j < 4; j++) {
        int idx = base + j;
        if (idx < n) data[idx] = run;
        run += v[j];
    }
}

__global__ void k_scan3_rows(const int* __restrict__ cnt, int N, const int* __restrict__ bsums,
                             int* __restrict__ row_start, int* __restrict__ fcur, int E) {
    __shared__ int sh[256];
    int t = threadIdx.x;
    int base = blockIdx.x * 1024 + t * 4;
    int v[4]; int s = 0;
#pragma unroll
    for (int j = 0; j < 4; j++) { int idx = base + j; v[j] = (idx < N) ? cnt[idx] : 0; s += v[j]; }
    sh[t] = s; __syncthreads();
    int x = s;
    for (int off = 1; off < 256; off <<= 1) {
        int y = (t >= off) ? sh[t - off] : 0;
        __syncthreads();
        x += y; sh[t] = x;
        __syncthreads();
    }
    int run = bsums[blockIdx.x] + (x - s);
#pragma unroll
    for (int j = 0; j < 4; j++) {
        int idx = base + j;
        if (idx < N) { row_start[idx] = run; fcur[idx] = run; }
        run += v[j];
    }
    if (blockIdx.x == 0 && t == 0) row_start[N] = E;
}

// ---------------- MFMA GEMM: C[M x 128] = [A1|A2] @ W  (+bias) (*dis) (relu) ----
// BM=128, BN=128, BK=32, 256 threads (4 waves), wave tile 32x128 (2x8 frags 16x16x32).
// OUT: 0 = bf16 row (256B), 1 = fp8 e4m3 row (128B).

template<bool A1BF, bool BIAS, bool RELU, bool SCALE, int OUT>
__global__ __launch_bounds__(256) void k_mgemm(
    const void* __restrict__ A1v, int K1,
    const u32* __restrict__ A2, int K2,
    const u16* __restrict__ Wt,
    const float* __restrict__ bias,
    const float* __restrict__ dis,
    void* __restrict__ Cv, int M)
{
    __shared__ u32 Al[128][16];
    __shared__ u32 Bl[128][16];

    const int tid = threadIdx.x;
    const int l = tid & 63;
    const int w = tid >> 6;
    const int g = l >> 4;      // k-group 0..3
    const int lr = l & 15;
    const int blockRow = blockIdx.x * 128;
    const int K = K1 + K2;

    const int sr = tid >> 1;
    const int sh_ = tid & 1;
    int arow = blockRow + sr; if (arow >= M) arow = M - 1;

    f32x4 acc[2][8];
#pragma unroll
    for (int i = 0; i < 2; i++)
#pragma unroll
        for (int j = 0; j < 8; j++) acc[i][j] = (f32x4)0.f;

    const int ssw = (sr >> 1) & 3;
    const u32* wt32 = (const u32*)Wt;

    for (int k0 = 0; k0 < K; k0 += 32) {
        u32 pk[8];
        if (k0 < K1) {
            if (A1BF) {
                const u32* src = (const u32*)A1v + (size_t)arow * (K1 >> 1) + ((k0 + sh_ * 16) >> 1);
                uint4 a = *(const uint4*)src;
                uint4 b = *(const uint4*)(src + 4);
                pk[0] = a.x; pk[1] = a.y; pk[2] = a.z; pk[3] = a.w;
                pk[4] = b.x; pk[5] = b.y; pk[6] = b.z; pk[7] = b.w;
            } else {
                const float* src = (const float*)A1v + (size_t)arow * K1 + k0 + sh_ * 16;
                float4 f0 = *(const float4*)(src + 0);
                float4 f1 = *(const float4*)(src + 4);
                float4 f2 = *(const float4*)(src + 8);
                float4 f3 = *(const float4*)(src + 12);
                pk[0] = pack_bf16(f0.x, f0.y); pk[1] = pack_bf16(f0.z, f0.w);
                pk[2] = pack_bf16(f1.x, f1.y); pk[3] = pack_bf16(f1.z, f1.w);
                pk[4] = pack_bf16(f2.x, f2.y); pk[5] = pack_bf16(f2.z, f2.w);
                pk[6] = pack_bf16(f3.x, f3.y); pk[7] = pack_bf16(f3.z, f3.w);
            }
        } else {
            const u32* src = A2 + (size_t)arow * (K2 >> 1) + ((k0 - K1 + sh_ * 16) >> 1);
            uint4 a = *(const uint4*)src;
            uint4 b = *(const uint4*)(src + 4);
            pk[0] = a.x; pk[1] = a.y; pk[2] = a.z; pk[3] = a.w;
            pk[4] = b.x; pk[5] = b.y; pk[6] = b.z; pk[7] = b.w;
        }
        {
            int b0 = (sh_ * 2 + ssw) & 3;
            int b1 = (sh_ * 2 + 1 + ssw) & 3;
            *(uint4*)&Al[sr][b0 * 4] = make_uint4(pk[0], pk[1], pk[2], pk[3]);
            *(uint4*)&Al[sr][b1 * 4] = make_uint4(pk[4], pk[5], pk[6], pk[7]);
        }
        {
            const u32* src = wt32 + (size_t)sr * (K >> 1) + ((k0 + sh_ * 16) >> 1);
            uint4 a = *(const uint4*)src;
            uint4 b = *(const uint4*)(src + 4);
            int b0 = (sh_ * 2 + ssw) & 3;
            int b1 = (sh_ * 2 + 1 + ssw) & 3;
            *(uint4*)&Bl[sr][b0 * 4] = a;
            *(uint4*)&Bl[sr][b1 * 4] = b;
        }
        __syncthreads();

        bf16x8 af[2];
#pragma unroll
        for (int rf = 0; rf < 2; rf++) {
            int r = w * 32 + rf * 16 + lr;
            int blk = (g + ((r >> 1) & 3)) & 3;
            af[rf] = *(const bf16x8*)&Al[r][blk * 4];
        }
#pragma unroll
        for (int cb = 0; cb < 8; cb++) {
            int c = cb * 16 + lr;
            int blk = (g + ((c >> 1) & 3)) & 3;
            bf16x8 bf = *(const bf16x8*)&Bl[c][blk * 4];
            acc[0][cb] = __builtin_amdgcn_mfma_f32_16x16x32_bf16(af[0], bf, acc[0][cb], 0, 0, 0);
            acc[1][cb] = __builtin_amdgcn_mfma_f32_16x16x32_bf16(af[1], bf, acc[1][cb], 0, 0, 0);
        }
        __syncthreads();
    }

    // ---- epilogue ----
    float disv[2][4];
    if (SCALE) {
#pragma unroll
        for (int rf = 0; rf < 2; rf++)
#pragma unroll
            for (int j = 0; j < 4; j++) {
                int row = blockRow + w * 32 + rf * 16 + g * 4 + j;
                disv[rf][j] = (row < M) ? dis[row] : 0.f;
            }
    }
#pragma unroll
    for (int rf = 0; rf < 2; rf++) {
#pragma unroll
        for (int cb = 0; cb < 8; cb++) {
            int col = cb * 16 + lr;
            float bv = BIAS ? bias[col] : 0.f;
#pragma unroll
            for (int j = 0; j < 4; j++) {
                int row = blockRow + w * 32 + rf * 16 + g * 4 + j;
                if (row < M) {
                    float v = acc[rf][cb][j];
                    if (BIAS) v += bv;
                    if (SCALE) v *= disv[rf][j];
                    if (RELU) v = fmaxf(v, 0.f);
                    if (OUT == 0) {
                        ((u16*)Cv)[(size_t)row * 128 + col] = pack1_bf16(v);
                    } else {
                        ((u8*)Cv)[(size_t)row * 128 + col] = pack1_fp8(v);
                    }
                }
            }
        }
    }
}

// ---------------- gather1 (fp8 in, bf16 out) ----------------
// h[n] = relu(dis[n] * (sum_{s in N(n)} xls[s] + xls[n]) + b)
// xls rows: 128 fp8 = 128B; lane reads u16 (2 fp8 = features 2l, 2l+1).

__global__ __launch_bounds__(256) void k_gather1(
    const u16* __restrict__ xls, const int* __restrict__ row_start,
    const int* __restrict__ csr, const float* __restrict__ dis,
    const float* __restrict__ bias, u32* __restrict__ h, int N)
{
    int wave = threadIdx.x >> 6;
    int lane = threadIdx.x & 63;
    int n = blockIdx.x * 4 + wave;
    if (n >= N) return;
    int jb = row_start[n], je = row_start[n + 1];

    f32x2 sv = __builtin_amdgcn_cvt_pk_f32_fp8((int)xls[(size_t)n * 64 + lane], false);
    float acc0 = sv.x, acc1 = sv.y;

    int j = jb;
    for (; j + 3 < je; j += 4) {
        int s0 = csr[j], s1 = csr[j + 1], s2 = csr[j + 2], s3 = csr[j + 3];
        f32x2 v0 = __builtin_amdgcn_cvt_pk_f32_fp8((int)xls[(size_t)s0 * 64 + lane], false);
        f32x2 v1 = __builtin_amdgcn_cvt_pk_f32_fp8((int)xls[(size_t)s1 * 64 + lane], false);
        f32x2 v2 = __builtin_amdgcn_cvt_pk_f32_fp8((int)xls[(size_t)s2 * 64 + lane], false);
        f32x2 v3 = __builtin_amdgcn_cvt_pk_f32_fp8((int)xls[(size_t)s3 * 64 + lane], false);
        acc0 += v0.x + v1.x + v2.x + v3.x;
        acc1 += v0.y + v1.y + v2.y + v3.y;
    }
    for (; j < je; j++) {
        int s = csr[j];
        f32x2 v = __builtin_amdgcn_cvt_pk_f32_fp8((int)xls[(size_t)s * 64 + lane], false);
        acc0 += v.x;
        acc1 += v.y;
    }
    float d = dis[n];
    float2 bv = *(const float2*)&bias[lane * 2];
    float o0 = fmaxf(fmaf(d, acc0, bv.x), 0.f);
    float o1 = fmaxf(fmaf(d, acc1, bv.y), 0.f);
    h[(size_t)n * 64 + lane] = pack_bf16(o0, o1);
}

// ---------------- gather2 + final (fp8 in, log_softmax out, fused) ----------------

__global__ __launch_bounds__(256) void k_gather2f(
    const u16* __restrict__ xls, const int* __restrict__ row_start,
    const int* __restrict__ csr, const float* __restrict__ dis,
    const float* __restrict__ bias, const float* __restrict__ Wl,
    const float* __restrict__ bl, float* __restrict__ out, int N)
{
    int wave = threadIdx.x >> 6;
    int lane = threadIdx.x & 63;
    int n = blockIdx.x * 4 + wave;
    if (n >= N) return;
    int jb = row_start[n], je = row_start[n + 1];

    f32x2 sv = __builtin_amdgcn_cvt_pk_f32_fp8((int)xls[(size_t)n * 64 + lane], false);
    float acc0 = sv.x, acc1 = sv.y;

    int j = jb;
    for (; j + 3 < je; j += 4) {
        int s0 = csr[j], s1 = csr[j + 1], s2 = csr[j + 2], s3 = csr[j + 3];
        f32x2 v0 = __builtin_amdgcn_cvt_pk_f32_fp8((int)xls[(size_t)s0 * 64 + lane], false);
        f32x2 v1 = __builtin_amdgcn_cvt_pk_f32_fp8((int)xls[(size_t)s1 * 64 + lane], false);
        f32x2 v2 = __builtin_amdgcn_cvt_pk_f32_fp8((int)xls[(size_t)s2 * 64 + lane], false);
        f32x2 v3 = __builtin_amdgcn_cvt_pk_f32_fp8((int)xls[(size_t)s3 * 64 + lane], false);
        acc0 += v0.x + v1.x + v2.x + v3.x;
        acc1 += v0.y + v1.y + v2.y + v3.y;
    }
    for (; j < je; j++) {
        int s = csr[j];
        f32x2 v = __builtin_amdgcn_cvt_pk_f32_fp8((int)xls[(size_t)s * 64 + lane], false);
        acc0 += v.x;
        acc1 += v.y;
    }
    float d = dis[n];
    float2 bv = *(const float2*)&bias[lane * 2];
    float h0 = fmaxf(fmaf(d, acc0, bv.x), 0.f);
    float h1 = fmaxf(fmaf(d, acc1, bv.y), 0.f);

    // logits: features 2l (h0), 2l+1 (h1); Wl is [128][2]
    float4 wl = *(const float4*)&Wl[lane * 4];
    float p0 = h0 * wl.x + h1 * wl.z;
    float p1 = h0 * wl.y + h1 * wl.w;
#pragma unroll
    for (int off = 32; off > 0; off >>= 1) {
        p0 += __shfl_down(p0, off);
        p1 += __shfl_down(p1, off);
    }
    if (lane == 0) {
        float z0 = p0 + bl[0], z1 = p1 + bl[1];
        float m = fmaxf(z0, z1);
        float ls = m + logf(expf(z0 - m) + expf(z1 - m));
        out[(size_t)n * 2 + 0] = z0 - ls;
        out[(size_t)n * 2 + 1] = z1 - ls;
    }
}

// ---------------- launch ----------------

extern "C" void kernel_launch(void* const* d_in, const int* in_sizes, int n_in,
                              void* d_out, int out_size, void* d_ws, size_t ws_size,
                              hipStream_t stream) {
    const float* high  = (const float*)d_in[0];
    const float* low   = (const float*)d_in[1];
    const int*   ei    = (const int*)d_in[2];
    const float* W_emb = (const float*)d_in[3];
    const float* b_emb = (const float*)d_in[4];
    const float* W1    = (const float*)d_in[5];
    const float* b1    = (const float*)d_in[6];
    const float* W2    = (const float*)d_in[7];
    const float* b2    = (const float*)d_in[8];
    const float* Wl    = (const float*)d_in[9];
    const float* bl    = (const float*)d_in[10];

    int N = in_sizes[0] / HIGH;
    int E = in_sizes[2] / 2;
    const int* srcp = ei;
    const int* dstp = ei + E;
    float* out = (float*)d_out;

    int NB = (N + 255) >> BINSHIFT;
    int NSCAN = NB * NBLK;

    char* ws = (char*)d_ws;
    size_t off = 0;
    auto alloc = [&](size_t b) { size_t o = off; off += (b + 255) & ~(size_t)255; return o; };
    float* dis       = (float*)(ws + alloc((size_t)N * 4));
    int*   cnt       = (int*)  (ws + alloc((size_t)N * 4));
    int*   row_start = (int*)  (ws + alloc((size_t)(N + 1) * 4));
    int*   fcur      = (int*)  (ws + alloc((size_t)N * 4));
    int*   bsums     = (int*)  (ws + alloc(4096));
    int*   cnts      = (int*)  (ws + alloc((size_t)NSCAN * 4));
    u32*   packed    = (u32*)  (ws + alloc((size_t)E * 4));
    int*   csr       = (int*)  (ws + alloc((size_t)E * 4));
    u16*   Wt1       = (u16*)  (ws + alloc((size_t)512 * 128 * 2));
    u16*   Wt2       = (u16*)  (ws + alloc((size_t)128 * 128 * 2));
    u16*   WtE       = (u16*)  (ws + alloc((size_t)64 * 128 * 2));
    u16*   bufE      = (u16*)  (ws + alloc((size_t)N * 128 * 2));  // bf16 low_emb
    u8*    bufX      = (u8*)   (ws + alloc((size_t)N * 128));      // fp8 xls
    u16*   bufH      = (u16*)  (ws + alloc((size_t)N * 128 * 2));  // bf16 h1
    (void)ws_size; (void)n_in; (void)out_size;

    int nbS = (NSCAN + 1023) / 1024;
    int nbN = (N + 1023) / 1024;
    int mt  = (N + 127) / 128;

    // ---- weight transpose+cast (tiny) ----
    k_castw<<<(512 * 128 + 255) / 256, 256, 0, stream>>>(W1, Wt1, 512);
    k_castw<<<(128 * 128 + 255) / 256, 256, 0, stream>>>(W2, Wt2, 128);
    k_castw<<<(64 * 128 + 255) / 256, 256, 0, stream>>>(W_emb, WtE, 64);

    // ---- binned CSR build ----
    k_binhist<<<NBLK, 256, 0, stream>>>(dstp, E, cnts, NB);
    k_scan1<<<nbS, 256, 0, stream>>>(cnts, NSCAN, bsums);
    k_scan2<<<1, 64, 0, stream>>>(bsums, nbS);
    k_scan3_flat<<<nbS, 256, 0, stream>>>(cnts, NSCAN, bsums);
    k_binscatter<<<NBLK, 256, 0, stream>>>(srcp, dstp, E, cnts, packed, NB);
    k_zero_int<<<(N + 255) / 256, 256, 0, stream>>>(cnt, N);
    k_hist2<<<NB, 256, 0, stream>>>(packed, cnts, E, cnt, NB);
    k_dis<<<(N + 255) / 256, 256, 0, stream>>>(cnt, dis, N);
    k_scan1<<<nbN, 256, 0, stream>>>(cnt, N, bsums);
    k_scan2<<<1, 64, 0, stream>>>(bsums, nbN);
    k_scan3_rows<<<nbN, 256, 0, stream>>>(cnt, N, bsums, row_start, fcur, E);
    k_fill2<<<NB, 256, 0, stream>>>(packed, cnts, E, fcur, csr, NB);

    // ---- network ----
    // low_emb = relu(low @ W_emb + b_emb)                 -> bufE (bf16)
    k_mgemm<false, true, true, false, 0><<<mt, 256, 0, stream>>>(
        low, LOWD, nullptr, 0, WtE, b_emb, nullptr, bufE, N);
    // xls1 = ([high | low_emb] @ W1) * dis                -> bufX (fp8)
    k_mgemm<false, false, false, true, 1><<<mt, 256, 0, stream>>>(
        high, HIGH, (const u32*)bufE, EMB, Wt1, nullptr, dis, bufX, N);
    // h1 = relu(dis * (gather(xls1) + self) + b1)         -> bufH (bf16)
    k_gather1<<<(N + 3) / 4, 256, 0, stream>>>(
        (const u16*)bufX, row_start, csr, dis, b1, (u32*)bufH, N);
    // xls2 = (h1 @ W2) * dis                              -> bufX (fp8)
    k_mgemm<true, false, false, true, 1><<<mt, 256, 0, stream>>>(
        bufH, HID, nullptr, 0, Wt2, nullptr, dis, bufX, N);
    // out = log_softmax(dis * (gather(xls2) + self) + b2 @ W_lin + b_lin)  [fused]
    k_gather2f<<<(N + 3) / 4, 256, 0, stream>>>(
        (const u16*)bufX, row_start, csr, dis, b2, Wl, bl, out, N);
}

// Round 6
// 450.046 us; speedup vs baseline: 2.4886x; 1.2555x over previous
//
#include <hip/hip_runtime.h>

#define HIGH 384
#define LOWD 64
#define EMB  128
#define HID  128

// Binned CSR build: bin = dst >> 8. Requires N <= 131072 (src packs in 17 bits).
#define BINSHIFT 8
#define SRCBITS  17
#define SRCMASK  0x1FFFF
#define NBLK     256

typedef unsigned int u32;
typedef unsigned short u16;
typedef unsigned char u8;
typedef __attribute__((ext_vector_type(8))) short bf16x8;
typedef __attribute__((ext_vector_type(4))) float f32x4;
typedef __attribute__((ext_vector_type(2))) float f32x2;

__device__ __forceinline__ u32 pack_bf16(float a, float b) {
    u32 ua = __builtin_bit_cast(u32, a);
    u32 ub = __builtin_bit_cast(u32, b);
    ua += 0x7fffu + ((ua >> 16) & 1u);
    ub += 0x7fffu + ((ub >> 16) & 1u);
    return (ua >> 16) | (ub & 0xffff0000u);
}
__device__ __forceinline__ u16 pack1_bf16(float a) {
    u32 ua = __builtin_bit_cast(u32, a);
    ua += 0x7fffu + ((ua >> 16) & 1u);
    return (u16)(ua >> 16);
}
__device__ __forceinline__ u8 pack1_fp8(float a) {
    int r = __builtin_amdgcn_cvt_pk_fp8_f32(a, a, 0, false);
    return (u8)(r & 0xff);
}

// ---------------- utility kernels ----------------

__global__ void k_dis(const int* __restrict__ cnt, float* __restrict__ dis, int N) {
    int i = blockIdx.x * 256 + threadIdx.x;
    if (i < N) dis[i] = rsqrtf((float)cnt[i] + 1.0f);
}

// All three weights: W[K][128] fp32 -> Wt[128][K] bf16
__global__ void k_castw_all(const float* __restrict__ W1, u16* __restrict__ Wt1,
                            const float* __restrict__ W2, u16* __restrict__ Wt2,
                            const float* __restrict__ WE, u16* __restrict__ WtE) {
    int i = blockIdx.x * 256 + threadIdx.x;
    if (i < 65536) {                       // W1: K=512
        int k = i >> 7, c = i & 127;
        Wt1[c * 512 + k] = pack1_bf16(W1[i]);
    } else if (i < 81920) {                // W2: K=128
        int j = i - 65536;
        int k = j >> 7, c = j & 127;
        Wt2[c * 128 + k] = pack1_bf16(W2[j]);
    } else if (i < 90112) {                // W_emb: K=64
        int j = i - 81920;
        int k = j >> 7, c = j & 127;
        WtE[c * 64 + k] = pack1_bf16(WE[j]);
    }
}

// ---------------- binned edge partition ----------------

__global__ __launch_bounds__(256) void k_binhist(const int* __restrict__ dst, int E,
                                                 int* __restrict__ cnts, int NB) {
    __shared__ int hist[512];
    for (int b = threadIdx.x; b < NB; b += 256) hist[b] = 0;
    __syncthreads();
    int CH = (E + gridDim.x - 1) / gridDim.x;
    int e0 = blockIdx.x * CH;
    int e1 = min(E, e0 + CH);
    for (int e = e0 + threadIdx.x; e < e1; e += 256)
        atomicAdd(&hist[dst[e] >> BINSHIFT], 1);
    __syncthreads();
    for (int b = threadIdx.x; b < NB; b += 256)
        cnts[b * NBLK + blockIdx.x] = hist[b];
}

__global__ __launch_bounds__(256) void k_binscatter(const int* __restrict__ src,
                                                    const int* __restrict__ dst, int E,
                                                    const int* __restrict__ cnts,
                                                    u32* __restrict__ packed, int NB) {
    __shared__ int cur[512];
    for (int b = threadIdx.x; b < NB; b += 256) cur[b] = cnts[b * NBLK + blockIdx.x];
    __syncthreads();
    int CH = (E + gridDim.x - 1) / gridDim.x;
    int e0 = blockIdx.x * CH;
    int e1 = min(E, e0 + CH);
    for (int e = e0 + threadIdx.x; e < e1; e += 256) {
        int d = dst[e];
        int s = src[e];
        int bin = d >> BINSHIFT;
        int pos = atomicAdd(&cur[bin], 1);
        packed[pos] = (u32)s | ((u32)(d & 255) << SRCBITS);
    }
}

// Degree histogram: one block per bin, LDS-private window (bins tile the node range).
__global__ __launch_bounds__(256) void k_hist2(const u32* __restrict__ packed,
                                               const int* __restrict__ cnts, int E,
                                               int* __restrict__ cnt, int NB, int N) {
    __shared__ int hist[256];
    int t = threadIdx.x;
    hist[t] = 0;
    __syncthreads();
    int b = blockIdx.x;
    int begin = cnts[b * NBLK];
    int end = (b + 1 < NB) ? cnts[(b + 1) * NBLK] : E;
    for (int e = begin + t; e < end; e += 256)
        atomicAdd(&hist[packed[e] >> SRCBITS], 1);
    __syncthreads();
    int idx = (b << BINSHIFT) + t;
    if (idx < N) cnt[idx] = hist[t];
}

// CSR fill: LDS cursor window; csr stores word offsets (src * 32).
__global__ __launch_bounds__(256) void k_fill2(const u32* __restrict__ packed,
                                               const int* __restrict__ cnts, int E,
                                               const int* __restrict__ row_start,
                                               int* __restrict__ csr, int NB, int N) {
    __shared__ int cur[256];
    int t = threadIdx.x;
    int b = blockIdx.x;
    int base = b << BINSHIFT;
    cur[t] = row_start[min(base + t, N)];
    __syncthreads();
    int begin = cnts[b * NBLK];
    int end = (b + 1 < NB) ? cnts[(b + 1) * NBLK] : E;
    for (int e = begin + t; e < end; e += 256) {
        u32 p = packed[e];
        int pos = atomicAdd(&cur[p >> SRCBITS], 1);
        csr[pos] = (int)((p & SRCMASK) << 5);
    }
}

// ---------------- scan (3-kernel, generic) ----------------

__global__ void k_scan1(const int* __restrict__ in, int n, int* __restrict__ bsums) {
    __shared__ int sh[256];
    int t = threadIdx.x;
    int base = blockIdx.x * 1024 + t * 4;
    int s = 0;
#pragma unroll
    for (int j = 0; j < 4; j++) { int idx = base + j; s += (idx < n) ? in[idx] : 0; }
    sh[t] = s; __syncthreads();
    for (int off = 128; off > 0; off >>= 1) {
        if (t < off) sh[t] += sh[t + off];
        __syncthreads();
    }
    if (t == 0) bsums[blockIdx.x] = sh[0];
}

__global__ void k_scan2(int* bsums, int nb) {
    if (threadIdx.x == 0 && blockIdx.x == 0) {
        int run = 0;
        for (int i = 0; i < nb; i++) { int v = bsums[i]; bsums[i] = run; run += v; }
    }
}

__global__ void k_scan3_flat(int* __restrict__ data, int n, const int* __restrict__ bsums) {
    __shared__ int sh[256];
    int t = threadIdx.x;
    int base = blockIdx.x * 1024 + t * 4;
    int v[4]; int s = 0;
#pragma unroll
    for (int j = 0; j < 4; j++) { int idx = base + j; v[j] = (idx < n) ? data[idx] : 0; s += v[j]; }
    sh[t] = s; __syncthreads();
    int x = s;
    for (int off = 1; off < 256; off <<= 1) {
        int y = (t >= off) ? sh[t - off] : 0;
        __syncthreads();
        x += y; sh[t] = x;
        __syncthreads();
    }
    int run = bsums[blockIdx.x] + (x - s);
#pragma unroll
    for (int j = 0; j < 4; j++) {
        int idx = base + j;
        if (idx < n) data[idx] = run;
        run += v[j];
    }
}

__global__ void k_scan3_rows(const int* __restrict__ cnt, int N, const int* __restrict__ bsums,
                             int* __restrict__ row_start, int E) {
    __shared__ int sh[256];
    int t = threadIdx.x;
    int base = blockIdx.x * 1024 + t * 4;
    int v[4]; int s = 0;
#pragma unroll
    for (int j = 0; j < 4; j++) { int idx = base + j; v[j] = (idx < N) ? cnt[idx] : 0; s += v[j]; }
    sh[t] = s; __syncthreads();
    int x = s;
    for (int off = 1; off < 256; off <<= 1) {
        int y = (t >= off) ? sh[t - off] : 0;
        __syncthreads();
        x += y; sh[t] = x;
        __syncthreads();
    }
    int run = bsums[blockIdx.x] + (x - s);
#pragma unroll
    for (int j = 0; j < 4; j++) {
        int idx = base + j;
        if (idx < N) row_start[idx] = run;
        run += v[j];
    }
    if (blockIdx.x == 0 && t == 0) row_start[N] = E;
}

// ---------------- MFMA GEMM: C[M x 128] = [A1|A2] @ W  (+bias) (*dis) (relu) ----
// BM=128, BN=128, BK=32, 256 threads (4 waves), wave tile 32x128 (2x8 frags 16x16x32).
// OUT: 0 = bf16 row (256B), 1 = fp8 e4m3 row (128B).

template<bool A1BF, bool BIAS, bool RELU, bool SCALE, int OUT>
__global__ __launch_bounds__(256) void k_mgemm(
    const void* __restrict__ A1v, int K1,
    const u32* __restrict__ A2, int K2,
    const u16* __restrict__ Wt,
    const float* __restrict__ bias,
    const float* __restrict__ dis,
    void* __restrict__ Cv, int M)
{
    __shared__ u32 Al[128][16];
    __shared__ u32 Bl[128][16];

    const int tid = threadIdx.x;
    const int l = tid & 63;
    const int w = tid >> 6;
    const int g = l >> 4;      // k-group 0..3
    const int lr = l & 15;
    const int blockRow = blockIdx.x * 128;
    const int K = K1 + K2;

    const int sr = tid >> 1;
    const int sh_ = tid & 1;
    int arow = blockRow + sr; if (arow >= M) arow = M - 1;

    f32x4 acc[2][8];
#pragma unroll
    for (int i = 0; i < 2; i++)
#pragma unroll
        for (int j = 0; j < 8; j++) acc[i][j] = (f32x4)0.f;

    const int ssw = (sr >> 1) & 3;
    const u32* wt32 = (const u32*)Wt;

    for (int k0 = 0; k0 < K; k0 += 32) {
        u32 pk[8];
        if (k0 < K1) {
            if (A1BF) {
                const u32* src = (const u32*)A1v + (size_t)arow * (K1 >> 1) + ((k0 + sh_ * 16) >> 1);
                uint4 a = *(const uint4*)src;
                uint4 b = *(const uint4*)(src + 4);
                pk[0] = a.x; pk[1] = a.y; pk[2] = a.z; pk[3] = a.w;
                pk[4] = b.x; pk[5] = b.y; pk[6] = b.z; pk[7] = b.w;
            } else {
                const float* src = (const float*)A1v + (size_t)arow * K1 + k0 + sh_ * 16;
                float4 f0 = *(const float4*)(src + 0);
                float4 f1 = *(const float4*)(src + 4);
                float4 f2 = *(const float4*)(src + 8);
                float4 f3 = *(const float4*)(src + 12);
                pk[0] = pack_bf16(f0.x, f0.y); pk[1] = pack_bf16(f0.z, f0.w);
                pk[2] = pack_bf16(f1.x, f1.y); pk[3] = pack_bf16(f1.z, f1.w);
                pk[4] = pack_bf16(f2.x, f2.y); pk[5] = pack_bf16(f2.z, f2.w);
                pk[6] = pack_bf16(f3.x, f3.y); pk[7] = pack_bf16(f3.z, f3.w);
            }
        } else {
            const u32* src = A2 + (size_t)arow * (K2 >> 1) + ((k0 - K1 + sh_ * 16) >> 1);
            uint4 a = *(const uint4*)src;
            uint4 b = *(const uint4*)(src + 4);
            pk[0] = a.x; pk[1] = a.y; pk[2] = a.z; pk[3] = a.w;
            pk[4] = b.x; pk[5] = b.y; pk[6] = b.z; pk[7] = b.w;
        }
        {
            int b0 = (sh_ * 2 + ssw) & 3;
            int b1 = (sh_ * 2 + 1 + ssw) & 3;
            *(uint4*)&Al[sr][b0 * 4] = make_uint4(pk[0], pk[1], pk[2], pk[3]);
            *(uint4*)&Al[sr][b1 * 4] = make_uint4(pk[4], pk[5], pk[6], pk[7]);
        }
        {
            const u32* src = wt32 + (size_t)sr * (K >> 1) + ((k0 + sh_ * 16) >> 1);
            uint4 a = *(const uint4*)src;
            uint4 b = *(const uint4*)(src + 4);
            int b0 = (sh_ * 2 + ssw) & 3;
            int b1 = (sh_ * 2 + 1 + ssw) & 3;
            *(uint4*)&Bl[sr][b0 * 4] = a;
            *(uint4*)&Bl[sr][b1 * 4] = b;
        }
        __syncthreads();

        bf16x8 af[2];
#pragma unroll
        for (int rf = 0; rf < 2; rf++) {
            int r = w * 32 + rf * 16 + lr;
            int blk = (g + ((r >> 1) & 3)) & 3;
            af[rf] = *(const bf16x8*)&Al[r][blk * 4];
        }
#pragma unroll
        for (int cb = 0; cb < 8; cb++) {
            int c = cb * 16 + lr;
            int blk = (g + ((c >> 1) & 3)) & 3;
            bf16x8 bf = *(const bf16x8*)&Bl[c][blk * 4];
            acc[0][cb] = __builtin_amdgcn_mfma_f32_16x16x32_bf16(af[0], bf, acc[0][cb], 0, 0, 0);
            acc[1][cb] = __builtin_amdgcn_mfma_f32_16x16x32_bf16(af[1], bf, acc[1][cb], 0, 0, 0);
        }
        __syncthreads();
    }

    // ---- epilogue ----
    float disv[2][4];
    if (SCALE) {
#pragma unroll
        for (int rf = 0; rf < 2; rf++)
#pragma unroll
            for (int j = 0; j < 4; j++) {
                int row = blockRow + w * 32 + rf * 16 + g * 4 + j;
                disv[rf][j] = (row < M) ? dis[row] : 0.f;
            }
    }
#pragma unroll
    for (int rf = 0; rf < 2; rf++) {
#pragma unroll
        for (int cb = 0; cb < 8; cb++) {
            int col = cb * 16 + lr;
            float bv = BIAS ? bias[col] : 0.f;
#pragma unroll
            for (int j = 0; j < 4; j++) {
                int row = blockRow + w * 32 + rf * 16 + g * 4 + j;
                if (row < M) {
                    float v = acc[rf][cb][j];
                    if (BIAS) v += bv;
                    if (SCALE) v *= disv[rf][j];
                    if (RELU) v = fmaxf(v, 0.f);
                    if (OUT == 0) {
                        ((u16*)Cv)[(size_t)row * 128 + col] = pack1_bf16(v);
                    } else {
                        ((u8*)Cv)[(size_t)row * 128 + col] = pack1_fp8(v);
                    }
                }
            }
        }
    }
}

// ---------------- wave-split gather (fp8 in), 2 edges per wave step ----------------
// Lanes 0-31 cover edge j's 128B row (u32 = 4 fp8/lane); lanes 32-63 edge j+1.
// Fold halves via shfl. csr entries are pre-shifted word offsets (src*32).
// MODE 0: write bf16 h row. MODE 1: fused logits + log_softmax.

template<int MODE>
__global__ __launch_bounds__(256) void k_gatherw(
    const u32* __restrict__ xls32, const int* __restrict__ row_start,
    const int* __restrict__ csr, const float* __restrict__ dis,
    const float* __restrict__ bias, const float* __restrict__ Wl,
    const float* __restrict__ bl, void* __restrict__ outv, int N)
{
    int wave = threadIdx.x >> 6;
    int lane = threadIdx.x & 63;
    int half = lane >> 5;
    int w32 = lane & 31;
    int n = blockIdx.x * 4 + wave;
    if (n >= N) return;
    int jb = row_start[n], je = row_start[n + 1];

    float a0 = 0.f, a1 = 0.f, a2 = 0.f, a3 = 0.f;
    {
        u32 v = xls32[(u32)n * 32 + w32];   // self row
        if (half == 0) {
            f32x2 lo = __builtin_amdgcn_cvt_pk_f32_fp8((int)v, false);
            f32x2 hi = __builtin_amdgcn_cvt_pk_f32_fp8((int)v, true);
            a0 = lo.x; a1 = lo.y; a2 = hi.x; a3 = hi.y;
        }
    }

    int j = jb;
    for (; j + 3 < je; j += 4) {
        int c0 = csr[j + 2 * half];
        int c1 = csr[j + 2 * half + 1];
        u32 v0 = xls32[(u32)c0 + w32];
        u32 v1 = xls32[(u32)c1 + w32];
        f32x2 l0 = __builtin_amdgcn_cvt_pk_f32_fp8((int)v0, false);
        f32x2 h0 = __builtin_amdgcn_cvt_pk_f32_fp8((int)v0, true);
        f32x2 l1 = __builtin_amdgcn_cvt_pk_f32_fp8((int)v1, false);
        f32x2 h1 = __builtin_amdgcn_cvt_pk_f32_fp8((int)v1, true);
        a0 += l0.x + l1.x; a1 += l0.y + l1.y;
        a2 += h0.x + h1.x; a3 += h0.y + h1.y;
    }
    if (j + 1 < je) {
        int c = csr[j + half];
        u32 v = xls32[(u32)c + w32];
        f32x2 lo = __builtin_amdgcn_cvt_pk_f32_fp8((int)v, false);
        f32x2 hi = __builtin_amdgcn_cvt_pk_f32_fp8((int)v, true);
        a0 += lo.x; a1 += lo.y; a2 += hi.x; a3 += hi.y;
        j += 2;
    }
    if (j < je) {
        int c = csr[j];
        u32 v = xls32[(u32)c + w32];
        if (half == 0) {
            f32x2 lo = __builtin_amdgcn_cvt_pk_f32_fp8((int)v, false);
            f32x2 hi = __builtin_amdgcn_cvt_pk_f32_fp8((int)v, true);
            a0 += lo.x; a1 += lo.y; a2 += hi.x; a3 += hi.y;
        }
    }

    // fold upper half into lower
    a0 += __shfl(a0, w32 + 32);
    a1 += __shfl(a1, w32 + 32);
    a2 += __shfl(a2, w32 + 32);
    a3 += __shfl(a3, w32 + 32);

    float d = dis[n];
    float4 bv = *(const float4*)&bias[w32 * 4];
    float h0v = fmaxf(fmaf(d, a0, bv.x), 0.f);
    float h1v = fmaxf(fmaf(d, a1, bv.y), 0.f);
    float h2v = fmaxf(fmaf(d, a2, bv.z), 0.f);
    float h3v = fmaxf(fmaf(d, a3, bv.w), 0.f);

    if (MODE == 0) {
        if (half == 0) {
            uint2 pw;
            pw.x = pack_bf16(h0v, h1v);
            pw.y = pack_bf16(h2v, h3v);
            *(uint2*)((u32*)outv + (size_t)n * 64 + w32 * 2) = pw;
        }
    } else {
        // logits: lane w32 holds features 4*w32 .. 4*w32+3; Wl is [128][2]
        float4 q0 = *(const float4*)&Wl[w32 * 8];
        float4 q1 = *(const float4*)&Wl[w32 * 8 + 4];
        float p0 = h0v * q0.x + h1v * q0.z + h2v * q1.x + h3v * q1.z;
        float p1 = h0v * q0.y + h1v * q0.w + h2v * q1.y + h3v * q1.w;
#pragma unroll
        for (int off = 16; off > 0; off >>= 1) {
            p0 += __shfl_down(p0, off);
            p1 += __shfl_down(p1, off);
        }
        if (lane == 0) {
            float z0 = p0 + bl[0], z1 = p1 + bl[1];
            float m = fmaxf(z0, z1);
            float ls = m + logf(expf(z0 - m) + expf(z1 - m));
            float* out = (float*)outv;
            out[(size_t)n * 2 + 0] = z0 - ls;
            out[(size_t)n * 2 + 1] = z1 - ls;
        }
    }
}

// ---------------- launch ----------------

extern "C" void kernel_launch(void* const* d_in, const int* in_sizes, int n_in,
                              void* d_out, int out_size, void* d_ws, size_t ws_size,
                              hipStream_t stream) {
    const float* high  = (const float*)d_in[0];
    const float* low   = (const float*)d_in[1];
    const int*   ei    = (const int*)d_in[2];
    const float* W_emb = (const float*)d_in[3];
    const float* b_emb = (const float*)d_in[4];
    const float* W1    = (const float*)d_in[5];
    const float* b1    = (const float*)d_in[6];
    const float* W2    = (const float*)d_in[7];
    const float* b2    = (const float*)d_in[8];
    const float* Wl    = (const float*)d_in[9];
    const float* bl    = (const float*)d_in[10];

    int N = in_sizes[0] / HIGH;
    int E = in_sizes[2] / 2;
    const int* srcp = ei;
    const int* dstp = ei + E;
    float* out = (float*)d_out;

    int NB = (N + 255) >> BINSHIFT;
    int NSCAN = NB * NBLK;

    char* ws = (char*)d_ws;
    size_t off = 0;
    auto alloc = [&](size_t b) { size_t o = off; off += (b + 255) & ~(size_t)255; return o; };
    float* dis       = (float*)(ws + alloc((size_t)N * 4));
    int*   cnt       = (int*)  (ws + alloc((size_t)N * 4));
    int*   row_start = (int*)  (ws + alloc((size_t)(N + 1) * 4));
    int*   bsums     = (int*)  (ws + alloc(4096));
    int*   cnts      = (int*)  (ws + alloc((size_t)NSCAN * 4));
    u32*   packed    = (u32*)  (ws + alloc((size_t)E * 4));
    int*   csr       = (int*)  (ws + alloc((size_t)E * 4));
    u16*   Wt1       = (u16*)  (ws + alloc((size_t)512 * 128 * 2));
    u16*   Wt2       = (u16*)  (ws + alloc((size_t)128 * 128 * 2));
    u16*   WtE       = (u16*)  (ws + alloc((size_t)64 * 128 * 2));
    u16*   bufE      = (u16*)  (ws + alloc((size_t)N * 128 * 2));  // bf16 low_emb
    u8*    bufX      = (u8*)   (ws + alloc((size_t)N * 128));      // fp8 xls
    u16*   bufH      = (u16*)  (ws + alloc((size_t)N * 128 * 2));  // bf16 h1
    (void)ws_size; (void)n_in; (void)out_size;

    int nbS = (NSCAN + 1023) / 1024;
    int nbN = (N + 1023) / 1024;
    int mt  = (N + 127) / 128;

    // ---- weight transpose+cast (one kernel) ----
    k_castw_all<<<(90112 + 255) / 256, 256, 0, stream>>>(W1, Wt1, W2, Wt2, W_emb, WtE);

    // ---- binned CSR build ----
    k_binhist<<<NBLK, 256, 0, stream>>>(dstp, E, cnts, NB);
    k_scan1<<<nbS, 256, 0, stream>>>(cnts, NSCAN, bsums);
    k_scan2<<<1, 64, 0, stream>>>(bsums, nbS);
    k_scan3_flat<<<nbS, 256, 0, stream>>>(cnts, NSCAN, bsums);
    k_binscatter<<<NBLK, 256, 0, stream>>>(srcp, dstp, E, cnts, packed, NB);
    k_hist2<<<NB, 256, 0, stream>>>(packed, cnts, E, cnt, NB, N);
    k_dis<<<(N + 255) / 256, 256, 0, stream>>>(cnt, dis, N);
    k_scan1<<<nbN, 256, 0, stream>>>(cnt, N, bsums);
    k_scan2<<<1, 64, 0, stream>>>(bsums, nbN);
    k_scan3_rows<<<nbN, 256, 0, stream>>>(cnt, N, bsums, row_start, E);
    k_fill2<<<NB, 256, 0, stream>>>(packed, cnts, E, row_start, csr, NB, N);

    // ---- network ----
    // low_emb = relu(low @ W_emb + b_emb)                 -> bufE (bf16)
    k_mgemm<false, true, true, false, 0><<<mt, 256, 0, stream>>>(
        low, LOWD, nullptr, 0, WtE, b_emb, nullptr, bufE, N);
    // xls1 = ([high | low_emb] @ W1) * dis                -> bufX (fp8)
    k_mgemm<false, false, false, true, 1><<<mt, 256, 0, stream>>>(
        high, HIGH, (const u32*)bufE, EMB, Wt1, nullptr, dis, bufX, N);
    // h1 = relu(dis * (gather(xls1) + self) + b1)         -> bufH (bf16)
    k_gatherw<0><<<(N + 3) / 4, 256, 0, stream>>>(
        (const u32*)bufX, row_start, csr, dis, b1, nullptr, nullptr, bufH, N);
    // xls2 = (h1 @ W2) * dis                              -> bufX (fp8)
    k_mgemm<true, false, false, true, 1><<<mt, 256, 0, stream>>>(
        bufH, HID, nullptr, 0, Wt2, nullptr, dis, bufX, N);
    // out = log_softmax((dis * (gather(xls2) + self) + b2) @ W_lin + b_lin)  [fused]
    k_gatherw<1><<<(N + 3) / 4, 256, 0, stream>>>(
        (const u32*)bufX, row_start, csr, dis, b2, Wl, bl, out, N);
}

// Round 7
// 395.475 us; speedup vs baseline: 2.8320x; 1.1380x over previous
//
#include <hip/hip_runtime.h>

#define HIGH 384
#define LOWD 64
#define EMB  128
#define HID  128

// Binned CSR build: bin = dst >> 8. Requires N <= 131072 (src packs in 17 bits).
#define BINSHIFT 8
#define SRCBITS  17
#define SRCMASK  0x1FFFF
#define NBLK     256

typedef unsigned int u32;
typedef unsigned short u16;
typedef unsigned char u8;
typedef __attribute__((ext_vector_type(8))) short bf16x8;
typedef __attribute__((ext_vector_type(4))) float f32x4;
typedef __attribute__((ext_vector_type(2))) float f32x2;

__device__ __forceinline__ u32 pack_bf16(float a, float b) {
    u32 ua = __builtin_bit_cast(u32, a);
    u32 ub = __builtin_bit_cast(u32, b);
    ua += 0x7fffu + ((ua >> 16) & 1u);
    ub += 0x7fffu + ((ub >> 16) & 1u);
    return (ua >> 16) | (ub & 0xffff0000u);
}
__device__ __forceinline__ u16 pack1_bf16(float a) {
    u32 ua = __builtin_bit_cast(u32, a);
    ua += 0x7fffu + ((ua >> 16) & 1u);
    return (u16)(ua >> 16);
}
__device__ __forceinline__ u8 pack1_fp8(float a) {
    int r = __builtin_amdgcn_cvt_pk_fp8_f32(a, a, 0, false);
    return (u8)(r & 0xff);
}

// ---------------- utility kernels ----------------

__global__ void k_dis(const int* __restrict__ cnt, float* __restrict__ dis, int N) {
    int i = blockIdx.x * 256 + threadIdx.x;
    if (i < N) dis[i] = rsqrtf((float)cnt[i] + 1.0f);
}

// All three weights: W[K][128] fp32 -> Wt[128][K] bf16
__global__ void k_castw_all(const float* __restrict__ W1, u16* __restrict__ Wt1,
                            const float* __restrict__ W2, u16* __restrict__ Wt2,
                            const float* __restrict__ WE, u16* __restrict__ WtE) {
    int i = blockIdx.x * 256 + threadIdx.x;
    if (i < 65536) {                       // W1: K=512
        int k = i >> 7, c = i & 127;
        Wt1[c * 512 + k] = pack1_bf16(W1[i]);
    } else if (i < 81920) {                // W2: K=128
        int j = i - 65536;
        int k = j >> 7, c = j & 127;
        Wt2[c * 128 + k] = pack1_bf16(W2[j]);
    } else if (i < 90112) {                // W_emb: K=64
        int j = i - 81920;
        int k = j >> 7, c = j & 127;
        WtE[c * 64 + k] = pack1_bf16(WE[j]);
    }
}

// ---------------- binned edge partition ----------------

__global__ __launch_bounds__(256) void k_binhist(const int* __restrict__ dst, int E,
                                                 int* __restrict__ cnts, int NB) {
    __shared__ int hist[512];
    for (int b = threadIdx.x; b < NB; b += 256) hist[b] = 0;
    __syncthreads();
    int CH = (E + gridDim.x - 1) / gridDim.x;
    int e0 = blockIdx.x * CH;
    int e1 = min(E, e0 + CH);
    for (int e = e0 + threadIdx.x; e < e1; e += 256)
        atomicAdd(&hist[dst[e] >> BINSHIFT], 1);
    __syncthreads();
    for (int b = threadIdx.x; b < NB; b += 256)
        cnts[b * NBLK + blockIdx.x] = hist[b];
}

__global__ __launch_bounds__(256) void k_binscatter(const int* __restrict__ src,
                                                    const int* __restrict__ dst, int E,
                                                    const int* __restrict__ cnts,
                                                    u32* __restrict__ packed, int NB) {
    __shared__ int cur[512];
    for (int b = threadIdx.x; b < NB; b += 256) cur[b] = cnts[b * NBLK + blockIdx.x];
    __syncthreads();
    int CH = (E + gridDim.x - 1) / gridDim.x;
    int e0 = blockIdx.x * CH;
    int e1 = min(E, e0 + CH);
    for (int e = e0 + threadIdx.x; e < e1; e += 256) {
        int d = dst[e];
        int s = src[e];
        int bin = d >> BINSHIFT;
        int pos = atomicAdd(&cur[bin], 1);
        packed[pos] = (u32)s | ((u32)(d & 255) << SRCBITS);
    }
}

// Degree histogram: one block per bin, LDS-private window (bins tile the node range).
__global__ __launch_bounds__(256) void k_hist2(const u32* __restrict__ packed,
                                               const int* __restrict__ cnts, int E,
                                               int* __restrict__ cnt, int NB, int N) {
    __shared__ int hist[256];
    int t = threadIdx.x;
    hist[t] = 0;
    __syncthreads();
    int b = blockIdx.x;
    int begin = cnts[b * NBLK];
    int end = (b + 1 < NB) ? cnts[(b + 1) * NBLK] : E;
    for (int e = begin + t; e < end; e += 256)
        atomicAdd(&hist[packed[e] >> SRCBITS], 1);
    __syncthreads();
    int idx = (b << BINSHIFT) + t;
    if (idx < N) cnt[idx] = hist[t];
}

// CSR fill: LDS cursor window; csr stores word offsets (src * 32).
__global__ __launch_bounds__(256) void k_fill2(const u32* __restrict__ packed,
                                               const int* __restrict__ cnts, int E,
                                               const int* __restrict__ row_start,
                                               int* __restrict__ csr, int NB, int N) {
    __shared__ int cur[256];
    int t = threadIdx.x;
    int b = blockIdx.x;
    int base = b << BINSHIFT;
    cur[t] = row_start[min(base + t, N)];
    __syncthreads();
    int begin = cnts[b * NBLK];
    int end = (b + 1 < NB) ? cnts[(b + 1) * NBLK] : E;
    for (int e = begin + t; e < end; e += 256) {
        u32 p = packed[e];
        int pos = atomicAdd(&cur[p >> SRCBITS], 1);
        csr[pos] = (int)((p & SRCMASK) << 5);
    }
}

// ---------------- scan (3-kernel, generic) ----------------

__global__ void k_scan1(const int* __restrict__ in, int n, int* __restrict__ bsums) {
    __shared__ int sh[256];
    int t = threadIdx.x;
    int base = blockIdx.x * 1024 + t * 4;
    int s = 0;
#pragma unroll
    for (int j = 0; j < 4; j++) { int idx = base + j; s += (idx < n) ? in[idx] : 0; }
    sh[t] = s; __syncthreads();
    for (int off = 128; off > 0; off >>= 1) {
        if (t < off) sh[t] += sh[t + off];
        __syncthreads();
    }
    if (t == 0) bsums[blockIdx.x] = sh[0];
}

__global__ void k_scan2(int* bsums, int nb) {
    if (threadIdx.x == 0 && blockIdx.x == 0) {
        int run = 0;
        for (int i = 0; i < nb; i++) { int v = bsums[i]; bsums[i] = run; run += v; }
    }
}

__global__ void k_scan3_flat(int* __restrict__ data, int n, const int* __restrict__ bsums) {
    __shared__ int sh[256];
    int t = threadIdx.x;
    int base = blockIdx.x * 1024 + t * 4;
    int v[4]; int s = 0;
#pragma unroll
    for (int j = 0; j < 4; j++) { int idx = base + j; v[j] = (idx < n) ? data[idx] : 0; s += v[j]; }
    sh[t] = s; __syncthreads();
    int x = s;
    for (int off = 1; off < 256; off <<= 1) {
        int y = (t >= off) ? sh[t - off] : 0;
        __syncthreads();
        x += y; sh[t] = x;
        __syncthreads();
    }
    int run = bsums[blockIdx.x] + (x - s);
#pragma unroll
    for (int j = 0; j < 4; j++) {
        int idx = base + j;
        if (idx < n) data[idx] = run;
        run += v[j];
    }
}

__global__ void k_scan3_rows(const int* __restrict__ cnt, int N, const int* __restrict__ bsums,
                             int* __restrict__ row_start, int E) {
    __shared__ int sh[256];
    int t = threadIdx.x;
    int base = blockIdx.x * 1024 + t * 4;
    int v[4]; int s = 0;
#pragma unroll
    for (int j = 0; j < 4; j++) { int idx = base + j; v[j] = (idx < N) ? cnt[idx] : 0; s += v[j]; }
    sh[t] = s; __syncthreads();
    int x = s;
    for (int off = 1; off < 256; off <<= 1) {
        int y = (t >= off) ? sh[t - off] : 0;
        __syncthreads();
        x += y; sh[t] = x;
        __syncthreads();
    }
    int run = bsums[blockIdx.x] + (x - s);
#pragma unroll
    for (int j = 0; j < 4; j++) {
        int idx = base + j;
        if (idx < N) row_start[idx] = run;
        run += v[j];
    }
    if (blockIdx.x == 0 && t == 0) row_start[N] = E;
}

// ---------------- MFMA GEMM (2-phase pipelined): C = [A1|A2] @ W (+bias)(*dis)(relu) ----
// BM=128, BN=128, BK=32, 256 threads (4 waves), wave tile 32x128 (2x8 frags 16x16x32).
// Double-buffered LDS; T14 issue-early/write-late: global loads for tile t+1 are issued
// BEFORE tile t's MFMA compute, ds_write after, one barrier per iter.
// OUT: 0 = bf16 row (256B), 1 = fp8 e4m3 row (128B).

template<bool A1BF, bool BIAS, bool RELU, bool SCALE, int OUT>
__global__ __launch_bounds__(256) void k_mgemm(
    const void* __restrict__ A1v, int K1,
    const u32* __restrict__ A2, int K2,
    const u16* __restrict__ Wt,
    const float* __restrict__ bias,
    const float* __restrict__ dis,
    void* __restrict__ Cv, int M)
{
    __shared__ u32 Als[2][128][16];
    __shared__ u32 Bls[2][128][16];

    const int tid = threadIdx.x;
    const int l = tid & 63;
    const int w = tid >> 6;
    const int g = l >> 4;      // k-group 0..3
    const int lr = l & 15;
    const int blockRow = blockIdx.x * 128;
    const int K = K1 + K2;
    const int T = K >> 5;

    const int sr = tid >> 1;
    const int sh_ = tid & 1;
    int arow = blockRow + sr; if (arow >= M) arow = M - 1;
    const int ssw = (sr >> 1) & 3;
    const int sb0 = (sh_ * 2 + ssw) & 3;
    const int sb1 = (sh_ * 2 + 1 + ssw) & 3;

    const float* a1f = (const float*)A1v + (size_t)arow * K1;
    const u32*   a1b = (const u32*)A1v + (size_t)arow * (K1 >> 1);
    const u32*   a2b = A2 + (size_t)arow * (K2 >> 1);
    const u32*   wtb = (const u32*)Wt + (size_t)sr * (K >> 1);

    f32x4 acc[2][8];
#pragma unroll
    for (int i = 0; i < 2; i++)
#pragma unroll
        for (int j = 0; j < 8; j++) acc[i][j] = (f32x4)0.f;

    u32 pk[8], wk[8];

    auto load_tile = [&](int k0) {
        if (k0 < K1) {
            if (A1BF) {
                const u32* src = a1b + ((k0 + sh_ * 16) >> 1);
                uint4 a = *(const uint4*)src;
                uint4 b = *(const uint4*)(src + 4);
                pk[0] = a.x; pk[1] = a.y; pk[2] = a.z; pk[3] = a.w;
                pk[4] = b.x; pk[5] = b.y; pk[6] = b.z; pk[7] = b.w;
            } else {
                const float* src = a1f + k0 + sh_ * 16;
                float4 f0 = *(const float4*)(src + 0);
                float4 f1 = *(const float4*)(src + 4);
                float4 f2 = *(const float4*)(src + 8);
                float4 f3 = *(const float4*)(src + 12);
                pk[0] = pack_bf16(f0.x, f0.y); pk[1] = pack_bf16(f0.z, f0.w);
                pk[2] = pack_bf16(f1.x, f1.y); pk[3] = pack_bf16(f1.z, f1.w);
                pk[4] = pack_bf16(f2.x, f2.y); pk[5] = pack_bf16(f2.z, f2.w);
                pk[6] = pack_bf16(f3.x, f3.y); pk[7] = pack_bf16(f3.z, f3.w);
            }
        } else {
            const u32* src = a2b + ((k0 - K1 + sh_ * 16) >> 1);
            uint4 a = *(const uint4*)src;
            uint4 b = *(const uint4*)(src + 4);
            pk[0] = a.x; pk[1] = a.y; pk[2] = a.z; pk[3] = a.w;
            pk[4] = b.x; pk[5] = b.y; pk[6] = b.z; pk[7] = b.w;
        }
        const u32* srcw = wtb + ((k0 + sh_ * 16) >> 1);
        uint4 a = *(const uint4*)srcw;
        uint4 b = *(const uint4*)(srcw + 4);
        wk[0] = a.x; wk[1] = a.y; wk[2] = a.z; wk[3] = a.w;
        wk[4] = b.x; wk[5] = b.y; wk[6] = b.z; wk[7] = b.w;
    };
    auto store_tile = [&](int buf) {
        *(uint4*)&Als[buf][sr][sb0 * 4] = make_uint4(pk[0], pk[1], pk[2], pk[3]);
        *(uint4*)&Als[buf][sr][sb1 * 4] = make_uint4(pk[4], pk[5], pk[6], pk[7]);
        *(uint4*)&Bls[buf][sr][sb0 * 4] = make_uint4(wk[0], wk[1], wk[2], wk[3]);
        *(uint4*)&Bls[buf][sr][sb1 * 4] = make_uint4(wk[4], wk[5], wk[6], wk[7]);
    };

    load_tile(0);
    store_tile(0);
    __syncthreads();

    for (int t = 0; t < T; t++) {
        const int cur = t & 1;
        const bool more = (t + 1 < T);
        if (more) load_tile((t + 1) << 5);   // issue global loads early

        bf16x8 af[2];
#pragma unroll
        for (int rf = 0; rf < 2; rf++) {
            int r = w * 32 + rf * 16 + lr;
            int blk = (g + ((r >> 1) & 3)) & 3;
            af[rf] = *(const bf16x8*)&Als[cur][r][blk * 4];
        }
#pragma unroll
        for (int cb = 0; cb < 8; cb++) {
            int c = cb * 16 + lr;
            int blk = (g + ((c >> 1) & 3)) & 3;
            bf16x8 bf = *(const bf16x8*)&Bls[cur][c][blk * 4];
            acc[0][cb] = __builtin_amdgcn_mfma_f32_16x16x32_bf16(af[0], bf, acc[0][cb], 0, 0, 0);
            acc[1][cb] = __builtin_amdgcn_mfma_f32_16x16x32_bf16(af[1], bf, acc[1][cb], 0, 0, 0);
        }
        if (more) store_tile(cur ^ 1);       // write late (vmcnt waits here)
        __syncthreads();
    }

    // ---- epilogue ----
    float disv[2][4];
    if (SCALE) {
#pragma unroll
        for (int rf = 0; rf < 2; rf++)
#pragma unroll
            for (int j = 0; j < 4; j++) {
                int row = blockRow + w * 32 + rf * 16 + g * 4 + j;
                disv[rf][j] = (row < M) ? dis[row] : 0.f;
            }
    }
#pragma unroll
    for (int rf = 0; rf < 2; rf++) {
#pragma unroll
        for (int cb = 0; cb < 8; cb++) {
            int col = cb * 16 + lr;
            float bv = BIAS ? bias[col] : 0.f;
#pragma unroll
            for (int j = 0; j < 4; j++) {
                int row = blockRow + w * 32 + rf * 16 + g * 4 + j;
                if (row < M) {
                    float v = acc[rf][cb][j];
                    if (BIAS) v += bv;
                    if (SCALE) v *= disv[rf][j];
                    if (RELU) v = fmaxf(v, 0.f);
                    if (OUT == 0) {
                        ((u16*)Cv)[(size_t)row * 128 + col] = pack1_bf16(v);
                    } else {
                        ((u8*)Cv)[(size_t)row * 128 + col] = pack1_fp8(v);
                    }
                }
            }
        }
    }
}

// ---------------- wave-split gather (fp8 in), 8-edge unroll ----------------
// Lanes 0-31 cover one edge's 128B row (u32 = 4 fp8/lane); lanes 32-63 the next.
// 8-edge main loop -> 4 independent row loads in flight per half-wave.
// csr entries are pre-shifted word offsets (src*32).
// MODE 0: write bf16 h row. MODE 1: fused logits + log_softmax.

template<int MODE>
__global__ __launch_bounds__(256) void k_gatherw(
    const u32* __restrict__ xls32, const int* __restrict__ row_start,
    const int* __restrict__ csr, const float* __restrict__ dis,
    const float* __restrict__ bias, const float* __restrict__ Wl,
    const float* __restrict__ bl, void* __restrict__ outv, int N)
{
    int wave = threadIdx.x >> 6;
    int lane = threadIdx.x & 63;
    int half = lane >> 5;
    int w32 = lane & 31;
    int n = blockIdx.x * 4 + wave;
    if (n >= N) return;
    int jb = row_start[n], je = row_start[n + 1];

    float a0 = 0.f, a1 = 0.f, a2 = 0.f, a3 = 0.f;
    {
        u32 v = xls32[(u32)n * 32 + w32];   // self row
        if (half == 0) {
            f32x2 lo = __builtin_amdgcn_cvt_pk_f32_fp8((int)v, false);
            f32x2 hi = __builtin_amdgcn_cvt_pk_f32_fp8((int)v, true);
            a0 = lo.x; a1 = lo.y; a2 = hi.x; a3 = hi.y;
        }
    }

    int j = jb;
    for (; j + 7 < je; j += 8) {
        int c0 = csr[j + 4 * half + 0];
        int c1 = csr[j + 4 * half + 1];
        int c2 = csr[j + 4 * half + 2];
        int c3 = csr[j + 4 * half + 3];
        u32 v0 = xls32[(u32)c0 + w32];
        u32 v1 = xls32[(u32)c1 + w32];
        u32 v2 = xls32[(u32)c2 + w32];
        u32 v3 = xls32[(u32)c3 + w32];
        f32x2 l0 = __builtin_amdgcn_cvt_pk_f32_fp8((int)v0, false);
        f32x2 h0 = __builtin_amdgcn_cvt_pk_f32_fp8((int)v0, true);
        f32x2 l1 = __builtin_amdgcn_cvt_pk_f32_fp8((int)v1, false);
        f32x2 h1 = __builtin_amdgcn_cvt_pk_f32_fp8((int)v1, true);
        f32x2 l2 = __builtin_amdgcn_cvt_pk_f32_fp8((int)v2, false);
        f32x2 h2 = __builtin_amdgcn_cvt_pk_f32_fp8((int)v2, true);
        f32x2 l3 = __builtin_amdgcn_cvt_pk_f32_fp8((int)v3, false);
        f32x2 h3 = __builtin_amdgcn_cvt_pk_f32_fp8((int)v3, true);
        a0 += (l0.x + l1.x) + (l2.x + l3.x);
        a1 += (l0.y + l1.y) + (l2.y + l3.y);
        a2 += (h0.x + h1.x) + (h2.x + h3.x);
        a3 += (h0.y + h1.y) + (h2.y + h3.y);
    }
    for (; j + 3 < je; j += 4) {
        int c0 = csr[j + 2 * half];
        int c1 = csr[j + 2 * half + 1];
        u32 v0 = xls32[(u32)c0 + w32];
        u32 v1 = xls32[(u32)c1 + w32];
        f32x2 l0 = __builtin_amdgcn_cvt_pk_f32_fp8((int)v0, false);
        f32x2 h0 = __builtin_amdgcn_cvt_pk_f32_fp8((int)v0, true);
        f32x2 l1 = __builtin_amdgcn_cvt_pk_f32_fp8((int)v1, false);
        f32x2 h1 = __builtin_amdgcn_cvt_pk_f32_fp8((int)v1, true);
        a0 += l0.x + l1.x; a1 += l0.y + l1.y;
        a2 += h0.x + h1.x; a3 += h0.y + h1.y;
    }
    if (j + 1 < je) {
        int c = csr[j + half];
        u32 v = xls32[(u32)c + w32];
        f32x2 lo = __builtin_amdgcn_cvt_pk_f32_fp8((int)v, false);
        f32x2 hi = __builtin_amdgcn_cvt_pk_f32_fp8((int)v, true);
        a0 += lo.x; a1 += lo.y; a2 += hi.x; a3 += hi.y;
        j += 2;
    }
    if (j < je) {
        int c = csr[j];
        u32 v = xls32[(u32)c + w32];
        if (half == 0) {
            f32x2 lo = __builtin_amdgcn_cvt_pk_f32_fp8((int)v, false);
            f32x2 hi = __builtin_amdgcn_cvt_pk_f32_fp8((int)v, true);
            a0 += lo.x; a1 += lo.y; a2 += hi.x; a3 += hi.y;
        }
    }

    // fold upper half into lower
    a0 += __shfl(a0, w32 + 32);
    a1 += __shfl(a1, w32 + 32);
    a2 += __shfl(a2, w32 + 32);
    a3 += __shfl(a3, w32 + 32);

    float d = dis[n];
    float4 bv = *(const float4*)&bias[w32 * 4];
    float h0v = fmaxf(fmaf(d, a0, bv.x), 0.f);
    float h1v = fmaxf(fmaf(d, a1, bv.y), 0.f);
    float h2v = fmaxf(fmaf(d, a2, bv.z), 0.f);
    float h3v = fmaxf(fmaf(d, a3, bv.w), 0.f);

    if (MODE == 0) {
        if (half == 0) {
            uint2 pw;
            pw.x = pack_bf16(h0v, h1v);
            pw.y = pack_bf16(h2v, h3v);
            *(uint2*)((u32*)outv + (size_t)n * 64 + w32 * 2) = pw;
        }
    } else {
        // logits: lane w32 holds features 4*w32 .. 4*w32+3; Wl is [128][2]
        float4 q0 = *(const float4*)&Wl[w32 * 8];
        float4 q1 = *(const float4*)&Wl[w32 * 8 + 4];
        float p0 = h0v * q0.x + h1v * q0.z + h2v * q1.x + h3v * q1.z;
        float p1 = h0v * q0.y + h1v * q0.w + h2v * q1.y + h3v * q1.w;
#pragma unroll
        for (int off = 16; off > 0; off >>= 1) {
            p0 += __shfl_down(p0, off);
            p1 += __shfl_down(p1, off);
        }
        if (lane == 0) {
            float z0 = p0 + bl[0], z1 = p1 + bl[1];
            float m = fmaxf(z0, z1);
            float ls = m + logf(expf(z0 - m) + expf(z1 - m));
            float* out = (float*)outv;
            out[(size_t)n * 2 + 0] = z0 - ls;
            out[(size_t)n * 2 + 1] = z1 - ls;
        }
    }
}

// ---------------- launch ----------------

extern "C" void kernel_launch(void* const* d_in, const int* in_sizes, int n_in,
                              void* d_out, int out_size, void* d_ws, size_t ws_size,
                              hipStream_t stream) {
    const float* high  = (const float*)d_in[0];
    const float* low   = (const float*)d_in[1];
    const int*   ei    = (const int*)d_in[2];
    const float* W_emb = (const float*)d_in[3];
    const float* b_emb = (const float*)d_in[4];
    const float* W1    = (const float*)d_in[5];
    const float* b1    = (const float*)d_in[6];
    const float* W2    = (const float*)d_in[7];
    const float* b2    = (const float*)d_in[8];
    const float* Wl    = (const float*)d_in[9];
    const float* bl    = (const float*)d_in[10];

    int N = in_sizes[0] / HIGH;
    int E = in_sizes[2] / 2;
    const int* srcp = ei;
    const int* dstp = ei + E;
    float* out = (float*)d_out;

    int NB = (N + 255) >> BINSHIFT;
    int NSCAN = NB * NBLK;

    char* ws = (char*)d_ws;
    size_t off = 0;
    auto alloc = [&](size_t b) { size_t o = off; off += (b + 255) & ~(size_t)255; return o; };
    float* dis       = (float*)(ws + alloc((size_t)N * 4));
    int*   cnt       = (int*)  (ws + alloc((size_t)N * 4));
    int*   row_start = (int*)  (ws + alloc((size_t)(N + 1) * 4));
    int*   bsums     = (int*)  (ws + alloc(4096));
    int*   cnts      = (int*)  (ws + alloc((size_t)NSCAN * 4));
    u32*   packed    = (u32*)  (ws + alloc((size_t)E * 4));
    int*   csr       = (int*)  (ws + alloc((size_t)E * 4));
    u16*   Wt1       = (u16*)  (ws + alloc((size_t)512 * 128 * 2));
    u16*   Wt2       = (u16*)  (ws + alloc((size_t)128 * 128 * 2));
    u16*   WtE       = (u16*)  (ws + alloc((size_t)64 * 128 * 2));
    u16*   bufE      = (u16*)  (ws + alloc((size_t)N * 128 * 2));  // bf16 low_emb
    u8*    bufX      = (u8*)   (ws + alloc((size_t)N * 128));      // fp8 xls
    u16*   bufH      = (u16*)  (ws + alloc((size_t)N * 128 * 2));  // bf16 h1
    (void)ws_size; (void)n_in; (void)out_size;

    int nbS = (NSCAN + 1023) / 1024;
    int nbN = (N + 1023) / 1024;
    int mt  = (N + 127) / 128;

    // ---- weight transpose+cast (one kernel) ----
    k_castw_all<<<(90112 + 255) / 256, 256, 0, stream>>>(W1, Wt1, W2, Wt2, W_emb, WtE);

    // ---- binned CSR build ----
    k_binhist<<<NBLK, 256, 0, stream>>>(dstp, E, cnts, NB);
    k_scan1<<<nbS, 256, 0, stream>>>(cnts, NSCAN, bsums);
    k_scan2<<<1, 64, 0, stream>>>(bsums, nbS);
    k_scan3_flat<<<nbS, 256, 0, stream>>>(cnts, NSCAN, bsums);
    k_binscatter<<<NBLK, 256, 0, stream>>>(srcp, dstp, E, cnts, packed, NB);
    k_hist2<<<NB, 256, 0, stream>>>(packed, cnts, E, cnt, NB, N);
    k_dis<<<(N + 255) / 256, 256, 0, stream>>>(cnt, dis, N);
    k_scan1<<<nbN, 256, 0, stream>>>(cnt, N, bsums);
    k_scan2<<<1, 64, 0, stream>>>(bsums, nbN);
    k_scan3_rows<<<nbN, 256, 0, stream>>>(cnt, N, bsums, row_start, E);
    k_fill2<<<NB, 256, 0, stream>>>(packed, cnts, E, row_start, csr, NB, N);

    // ---- network ----
    // low_emb = relu(low @ W_emb + b_emb)                 -> bufE (bf16)
    k_mgemm<false, true, true, false, 0><<<mt, 256, 0, stream>>>(
        low, LOWD, (const u32*)bufE, 0, WtE, b_emb, nullptr, bufE, N);
    // xls1 = ([high | low_emb] @ W1) * dis                -> bufX (fp8)
    k_mgemm<false, false, false, true, 1><<<mt, 256, 0, stream>>>(
        high, HIGH, (const u32*)bufE, EMB, Wt1, nullptr, dis, bufX, N);
    // h1 = relu(dis * (gather(xls1) + self) + b1)         -> bufH (bf16)
    k_gatherw<0><<<(N + 3) / 4, 256, 0, stream>>>(
        (const u32*)bufX, row_start, csr, dis, b1, nullptr, nullptr, bufH, N);
    // xls2 = (h1 @ W2) * dis                              -> bufX (fp8)
    k_mgemm<true, false, false, true, 1><<<mt, 256, 0, stream>>>(
        bufH, HID, (const u32*)bufH, 0, Wt2, nullptr, dis, bufX, N);
    // out = log_softmax((dis * (gather(xls2) + self) + b2) @ W_lin + b_lin)  [fused]
    k_gatherw<1><<<(N + 3) / 4, 256, 0, stream>>>(
        (const u32*)bufX, row_start, csr, dis, b2, Wl, bl, out, N);
}

// Round 8
// 371.797 us; speedup vs baseline: 3.0124x; 1.0637x over previous
//
#include <hip/hip_runtime.h>

#define HIGH 384
#define LOWD 64
#define EMB  128
#define HID  128

// Binned CSR build: bin = dst >> 8. Requires N <= 131072 (src packs in 17 bits).
#define BINSHIFT 8
#define SRCBITS  17
#define SRCMASK  0x1FFFF
#define NBLK     256

typedef unsigned int u32;
typedef unsigned short u16;
typedef unsigned char u8;
typedef __attribute__((ext_vector_type(8))) short bf16x8;
typedef __attribute__((ext_vector_type(4))) float f32x4;
typedef __attribute__((ext_vector_type(2))) float f32x2;

__device__ __forceinline__ u32 pack_bf16(float a, float b) {
    u32 ua = __builtin_bit_cast(u32, a);
    u32 ub = __builtin_bit_cast(u32, b);
    ua += 0x7fffu + ((ua >> 16) & 1u);
    ub += 0x7fffu + ((ub >> 16) & 1u);
    return (ua >> 16) | (ub & 0xffff0000u);
}
__device__ __forceinline__ u16 pack1_bf16(float a) {
    u32 ua = __builtin_bit_cast(u32, a);
    ua += 0x7fffu + ((ua >> 16) & 1u);
    return (u16)(ua >> 16);
}
__device__ __forceinline__ u8 pack1_fp8(float a) {
    int r = __builtin_amdgcn_cvt_pk_fp8_f32(a, a, 0, false);
    return (u8)(r & 0xff);
}

// ---------------- utility kernels ----------------

__global__ void k_dis(const int* __restrict__ cnt, float* __restrict__ dis, int N) {
    int i = blockIdx.x * 256 + threadIdx.x;
    if (i < N) dis[i] = rsqrtf((float)cnt[i] + 1.0f);
}

// All three weights: W[K][128] fp32 -> Wt[128][K] bf16
__global__ void k_castw_all(const float* __restrict__ W1, u16* __restrict__ Wt1,
                            const float* __restrict__ W2, u16* __restrict__ Wt2,
                            const float* __restrict__ WE, u16* __restrict__ WtE) {
    int i = blockIdx.x * 256 + threadIdx.x;
    if (i < 65536) {                       // W1: K=512
        int k = i >> 7, c = i & 127;
        Wt1[c * 512 + k] = pack1_bf16(W1[i]);
    } else if (i < 81920) {                // W2: K=128
        int j = i - 65536;
        int k = j >> 7, c = j & 127;
        Wt2[c * 128 + k] = pack1_bf16(W2[j]);
    } else if (i < 90112) {                // W_emb: K=64
        int j = i - 81920;
        int k = j >> 7, c = j & 127;
        WtE[c * 64 + k] = pack1_bf16(WE[j]);
    }
}

// ---------------- binned edge partition ----------------

__global__ __launch_bounds__(256) void k_binhist(const int* __restrict__ dst, int E,
                                                 int* __restrict__ cnts, int NB) {
    __shared__ int hist[512];
    for (int b = threadIdx.x; b < NB; b += 256) hist[b] = 0;
    __syncthreads();
    int CH = (E + gridDim.x - 1) / gridDim.x;
    int e0 = blockIdx.x * CH;
    int e1 = min(E, e0 + CH);
    for (int e = e0 + threadIdx.x; e < e1; e += 256)
        atomicAdd(&hist[dst[e] >> BINSHIFT], 1);
    __syncthreads();
    for (int b = threadIdx.x; b < NB; b += 256)
        cnts[b * NBLK + blockIdx.x] = hist[b];
}

__global__ __launch_bounds__(256) void k_binscatter(const int* __restrict__ src,
                                                    const int* __restrict__ dst, int E,
                                                    const int* __restrict__ cnts,
                                                    u32* __restrict__ packed, int NB) {
    __shared__ int cur[512];
    for (int b = threadIdx.x; b < NB; b += 256) cur[b] = cnts[b * NBLK + blockIdx.x];
    __syncthreads();
    int CH = (E + gridDim.x - 1) / gridDim.x;
    int e0 = blockIdx.x * CH;
    int e1 = min(E, e0 + CH);
    for (int e = e0 + threadIdx.x; e < e1; e += 256) {
        int d = dst[e];
        int s = src[e];
        int bin = d >> BINSHIFT;
        int pos = atomicAdd(&cur[bin], 1);
        packed[pos] = (u32)s | ((u32)(d & 255) << SRCBITS);
    }
}

// Degree histogram: one block per bin, LDS-private window (bins tile the node range).
__global__ __launch_bounds__(256) void k_hist2(const u32* __restrict__ packed,
                                               const int* __restrict__ cnts, int E,
                                               int* __restrict__ cnt, int NB, int N) {
    __shared__ int hist[256];
    int t = threadIdx.x;
    hist[t] = 0;
    __syncthreads();
    int b = blockIdx.x;
    int begin = cnts[b * NBLK];
    int end = (b + 1 < NB) ? cnts[(b + 1) * NBLK] : E;
    for (int e = begin + t; e < end; e += 256)
        atomicAdd(&hist[packed[e] >> SRCBITS], 1);
    __syncthreads();
    int idx = (b << BINSHIFT) + t;
    if (idx < N) cnt[idx] = hist[t];
}

// CSR fill: LDS cursor window; csr stores word offsets (src * 32).
__global__ __launch_bounds__(256) void k_fill2(const u32* __restrict__ packed,
                                               const int* __restrict__ cnts, int E,
                                               const int* __restrict__ row_start,
                                               int* __restrict__ csr, int NB, int N) {
    __shared__ int cur[256];
    int t = threadIdx.x;
    int b = blockIdx.x;
    int base = b << BINSHIFT;
    cur[t] = row_start[min(base + t, N)];
    __syncthreads();
    int begin = cnts[b * NBLK];
    int end = (b + 1 < NB) ? cnts[(b + 1) * NBLK] : E;
    for (int e = begin + t; e < end; e += 256) {
        u32 p = packed[e];
        int pos = atomicAdd(&cur[p >> SRCBITS], 1);
        csr[pos] = (int)((p & SRCMASK) << 5);
    }
}

// ---------------- scan (3-kernel, generic) ----------------

__global__ void k_scan1(const int* __restrict__ in, int n, int* __restrict__ bsums) {
    __shared__ int sh[256];
    int t = threadIdx.x;
    int base = blockIdx.x * 1024 + t * 4;
    int s = 0;
#pragma unroll
    for (int j = 0; j < 4; j++) { int idx = base + j; s += (idx < n) ? in[idx] : 0; }
    sh[t] = s; __syncthreads();
    for (int off = 128; off > 0; off >>= 1) {
        if (t < off) sh[t] += sh[t + off];
        __syncthreads();
    }
    if (t == 0) bsums[blockIdx.x] = sh[0];
}

__global__ void k_scan2(int* bsums, int nb) {
    if (threadIdx.x == 0 && blockIdx.x == 0) {
        int run = 0;
        for (int i = 0; i < nb; i++) { int v = bsums[i]; bsums[i] = run; run += v; }
    }
}

__global__ void k_scan3_flat(int* __restrict__ data, int n, const int* __restrict__ bsums) {
    __shared__ int sh[256];
    int t = threadIdx.x;
    int base = blockIdx.x * 1024 + t * 4;
    int v[4]; int s = 0;
#pragma unroll
    for (int j = 0; j < 4; j++) { int idx = base + j; v[j] = (idx < n) ? data[idx] : 0; s += v[j]; }
    sh[t] = s; __syncthreads();
    int x = s;
    for (int off = 1; off < 256; off <<= 1) {
        int y = (t >= off) ? sh[t - off] : 0;
        __syncthreads();
        x += y; sh[t] = x;
        __syncthreads();
    }
    int run = bsums[blockIdx.x] + (x - s);
#pragma unroll
    for (int j = 0; j < 4; j++) {
        int idx = base + j;
        if (idx < n) data[idx] = run;
        run += v[j];
    }
}

__global__ void k_scan3_rows(const int* __restrict__ cnt, int N, const int* __restrict__ bsums,
                             int* __restrict__ row_start, int E) {
    __shared__ int sh[256];
    int t = threadIdx.x;
    int base = blockIdx.x * 1024 + t * 4;
    int v[4]; int s = 0;
#pragma unroll
    for (int j = 0; j < 4; j++) { int idx = base + j; v[j] = (idx < N) ? cnt[idx] : 0; s += v[j]; }
    sh[t] = s; __syncthreads();
    int x = s;
    for (int off = 1; off < 256; off <<= 1) {
        int y = (t >= off) ? sh[t - off] : 0;
        __syncthreads();
        x += y; sh[t] = x;
        __syncthreads();
    }
    int run = bsums[blockIdx.x] + (x - s);
#pragma unroll
    for (int j = 0; j < 4; j++) {
        int idx = base + j;
        if (idx < N) row_start[idx] = run;
        run += v[j];
    }
    if (blockIdx.x == 0 && t == 0) row_start[N] = E;
}

// ---------------- MFMA GEMM (high-occupancy): C = [A1|A2] @ W (+bias)(*dis)(relu) ----
// BM=64, BN=128, BK=32, 256 threads (4 waves), wave tile 16x128 (1x8 frags 16x16x32).
// grid ~1563 blocks, 24KB LDS -> ~6 blocks/CU resident: latency hidden by TLP.
// OUT: 0 = bf16 row (256B), 1 = fp8 e4m3 row (128B).

template<bool A1BF, bool BIAS, bool RELU, bool SCALE, int OUT>
__global__ __launch_bounds__(256, 6) void k_mgemm(
    const void* __restrict__ A1v, int K1,
    const u32* __restrict__ A2, int K2,
    const u16* __restrict__ Wt,
    const float* __restrict__ bias,
    const float* __restrict__ dis,
    void* __restrict__ Cv, int M)
{
    __shared__ u32 Als[2][64][16];
    __shared__ u32 Bls[2][128][16];

    const int tid = threadIdx.x;
    const int l = tid & 63;
    const int w = tid >> 6;
    const int g = l >> 4;      // k-group 0..3
    const int lr = l & 15;
    const int blockRow = blockIdx.x * 64;
    const int K = K1 + K2;
    const int T = K >> 5;

    // A staging: 4 threads/row, each 4 u32 (8 bf16 of k)
    const int ar = tid >> 2;        // 0..63
    const int ak = tid & 3;         // k-block
    int arow = blockRow + ar; if (arow >= M) arow = M - 1;
    const int awb = (ak + ((ar >> 1) & 3)) & 3;       // swizzled write block

    // W staging: 2 threads/col, each 8 u32 (16 bf16 of k)
    const int wc = tid >> 1;        // 0..127 col
    const int wh = tid & 1;
    const int wsw = (wc >> 1) & 3;
    const int wb0 = (wh * 2 + wsw) & 3;
    const int wb1 = (wh * 2 + 1 + wsw) & 3;

    const float* a1f = (const float*)A1v + (size_t)arow * K1;
    const u32*   a1b = (const u32*)A1v + (size_t)arow * (K1 >> 1);
    const u32*   a2b = A2 + (size_t)arow * (K2 >> 1);
    const u32*   wtb = (const u32*)Wt + (size_t)wc * (K >> 1);

    f32x4 acc[8];
#pragma unroll
    for (int j = 0; j < 8; j++) acc[j] = (f32x4)0.f;

    u32 pa[4], wk[8];

    auto load_tile = [&](int k0) {
        if (k0 < K1) {
            if (A1BF) {
                uint4 a = *(const uint4*)(a1b + (k0 >> 1) + ak * 4);
                pa[0] = a.x; pa[1] = a.y; pa[2] = a.z; pa[3] = a.w;
            } else {
                const float* src = a1f + k0 + ak * 8;
                float4 f0 = *(const float4*)(src + 0);
                float4 f1 = *(const float4*)(src + 4);
                pa[0] = pack_bf16(f0.x, f0.y); pa[1] = pack_bf16(f0.z, f0.w);
                pa[2] = pack_bf16(f1.x, f1.y); pa[3] = pack_bf16(f1.z, f1.w);
            }
        } else {
            uint4 a = *(const uint4*)(a2b + ((k0 - K1) >> 1) + ak * 4);
            pa[0] = a.x; pa[1] = a.y; pa[2] = a.z; pa[3] = a.w;
        }
        const u32* srcw = wtb + ((k0 + wh * 16) >> 1);
        uint4 a = *(const uint4*)srcw;
        uint4 b = *(const uint4*)(srcw + 4);
        wk[0] = a.x; wk[1] = a.y; wk[2] = a.z; wk[3] = a.w;
        wk[4] = b.x; wk[5] = b.y; wk[6] = b.z; wk[7] = b.w;
    };
    auto store_tile = [&](int buf) {
        *(uint4*)&Als[buf][ar][awb * 4] = make_uint4(pa[0], pa[1], pa[2], pa[3]);
        *(uint4*)&Bls[buf][wc][wb0 * 4] = make_uint4(wk[0], wk[1], wk[2], wk[3]);
        *(uint4*)&Bls[buf][wc][wb1 * 4] = make_uint4(wk[4], wk[5], wk[6], wk[7]);
    };

    load_tile(0);
    store_tile(0);
    __syncthreads();

    for (int t = 0; t < T; t++) {
        const int cur = t & 1;
        const bool more = (t + 1 < T);
        if (more) load_tile((t + 1) << 5);   // issue global loads early

        bf16x8 af;
        {
            int r = w * 16 + lr;
            int blk = (g + ((r >> 1) & 3)) & 3;
            af = *(const bf16x8*)&Als[cur][r][blk * 4];
        }
#pragma unroll
        for (int cb = 0; cb < 8; cb++) {
            int c = cb * 16 + lr;
            int blk = (g + ((c >> 1) & 3)) & 3;
            bf16x8 bf = *(const bf16x8*)&Bls[cur][c][blk * 4];
            acc[cb] = __builtin_amdgcn_mfma_f32_16x16x32_bf16(af, bf, acc[cb], 0, 0, 0);
        }
        if (more) store_tile(cur ^ 1);       // write late
        __syncthreads();
    }

    // ---- epilogue ----
    float disv[4];
    if (SCALE) {
#pragma unroll
        for (int j = 0; j < 4; j++) {
            int row = blockRow + w * 16 + g * 4 + j;
            disv[j] = (row < M) ? dis[row] : 0.f;
        }
    }
#pragma unroll
    for (int cb = 0; cb < 8; cb++) {
        int col = cb * 16 + lr;
        float bv = BIAS ? bias[col] : 0.f;
#pragma unroll
        for (int j = 0; j < 4; j++) {
            int row = blockRow + w * 16 + g * 4 + j;
            if (row < M) {
                float v = acc[cb][j];
                if (BIAS) v += bv;
                if (SCALE) v *= disv[j];
                if (RELU) v = fmaxf(v, 0.f);
                if (OUT == 0) {
                    ((u16*)Cv)[(size_t)row * 128 + col] = pack1_bf16(v);
                } else {
                    ((u8*)Cv)[(size_t)row * 128 + col] = pack1_fp8(v);
                }
            }
        }
    }
}

// ---------------- wave-split gather (fp8 in), 8-edge unroll ----------------
// Lanes 0-31 cover one edge's 128B row (u32 = 4 fp8/lane); lanes 32-63 the next.
// csr entries are pre-shifted word offsets (src*32).
// MODE 0: write bf16 h row. MODE 1: fused logits + log_softmax.

template<int MODE>
__global__ __launch_bounds__(256) void k_gatherw(
    const u32* __restrict__ xls32, const int* __restrict__ row_start,
    const int* __restrict__ csr, const float* __restrict__ dis,
    const float* __restrict__ bias, const float* __restrict__ Wl,
    const float* __restrict__ bl, void* __restrict__ outv, int N)
{
    int wave = threadIdx.x >> 6;
    int lane = threadIdx.x & 63;
    int half = lane >> 5;
    int w32 = lane & 31;
    int n = blockIdx.x * 4 + wave;
    if (n >= N) return;
    int jb = row_start[n], je = row_start[n + 1];

    float a0 = 0.f, a1 = 0.f, a2 = 0.f, a3 = 0.f;
    {
        u32 v = xls32[(u32)n * 32 + w32];   // self row
        if (half == 0) {
            f32x2 lo = __builtin_amdgcn_cvt_pk_f32_fp8((int)v, false);
            f32x2 hi = __builtin_amdgcn_cvt_pk_f32_fp8((int)v, true);
            a0 = lo.x; a1 = lo.y; a2 = hi.x; a3 = hi.y;
        }
    }

    int j = jb;
    for (; j + 7 < je; j += 8) {
        int c0 = csr[j + 4 * half + 0];
        int c1 = csr[j + 4 * half + 1];
        int c2 = csr[j + 4 * half + 2];
        int c3 = csr[j + 4 * half + 3];
        u32 v0 = xls32[(u32)c0 + w32];
        u32 v1 = xls32[(u32)c1 + w32];
        u32 v2 = xls32[(u32)c2 + w32];
        u32 v3 = xls32[(u32)c3 + w32];
        f32x2 l0 = __builtin_amdgcn_cvt_pk_f32_fp8((int)v0, false);
        f32x2 h0 = __builtin_amdgcn_cvt_pk_f32_fp8((int)v0, true);
        f32x2 l1 = __builtin_amdgcn_cvt_pk_f32_fp8((int)v1, false);
        f32x2 h1 = __builtin_amdgcn_cvt_pk_f32_fp8((int)v1, true);
        f32x2 l2 = __builtin_amdgcn_cvt_pk_f32_fp8((int)v2, false);
        f32x2 h2 = __builtin_amdgcn_cvt_pk_f32_fp8((int)v2, true);
        f32x2 l3 = __builtin_amdgcn_cvt_pk_f32_fp8((int)v3, false);
        f32x2 h3 = __builtin_amdgcn_cvt_pk_f32_fp8((int)v3, true);
        a0 += (l0.x + l1.x) + (l2.x + l3.x);
        a1 += (l0.y + l1.y) + (l2.y + l3.y);
        a2 += (h0.x + h1.x) + (h2.x + h3.x);
        a3 += (h0.y + h1.y) + (h2.y + h3.y);
    }
    for (; j + 3 < je; j += 4) {
        int c0 = csr[j + 2 * half];
        int c1 = csr[j + 2 * half + 1];
        u32 v0 = xls32[(u32)c0 + w32];
        u32 v1 = xls32[(u32)c1 + w32];
        f32x2 l0 = __builtin_amdgcn_cvt_pk_f32_fp8((int)v0, false);
        f32x2 h0 = __builtin_amdgcn_cvt_pk_f32_fp8((int)v0, true);
        f32x2 l1 = __builtin_amdgcn_cvt_pk_f32_fp8((int)v1, false);
        f32x2 h1 = __builtin_amdgcn_cvt_pk_f32_fp8((int)v1, true);
        a0 += l0.x + l1.x; a1 += l0.y + l1.y;
        a2 += h0.x + h1.x; a3 += h0.y + h1.y;
    }
    if (j + 1 < je) {
        int c = csr[j + half];
        u32 v = xls32[(u32)c + w32];
        f32x2 lo = __builtin_amdgcn_cvt_pk_f32_fp8((int)v, false);
        f32x2 hi = __builtin_amdgcn_cvt_pk_f32_fp8((int)v, true);
        a0 += lo.x; a1 += lo.y; a2 += hi.x; a3 += hi.y;
        j += 2;
    }
    if (j < je) {
        int c = csr[j];
        u32 v = xls32[(u32)c + w32];
        if (half == 0) {
            f32x2 lo = __builtin_amdgcn_cvt_pk_f32_fp8((int)v, false);
            f32x2 hi = __builtin_amdgcn_cvt_pk_f32_fp8((int)v, true);
            a0 += lo.x; a1 += lo.y; a2 += hi.x; a3 += hi.y;
        }
    }

    // fold upper half into lower
    a0 += __shfl(a0, w32 + 32);
    a1 += __shfl(a1, w32 + 32);
    a2 += __shfl(a2, w32 + 32);
    a3 += __shfl(a3, w32 + 32);

    float d = dis[n];
    float4 bv = *(const float4*)&bias[w32 * 4];
    float h0v = fmaxf(fmaf(d, a0, bv.x), 0.f);
    float h1v = fmaxf(fmaf(d, a1, bv.y), 0.f);
    float h2v = fmaxf(fmaf(d, a2, bv.z), 0.f);
    float h3v = fmaxf(fmaf(d, a3, bv.w), 0.f);

    if (MODE == 0) {
        if (half == 0) {
            uint2 pw;
            pw.x = pack_bf16(h0v, h1v);
            pw.y = pack_bf16(h2v, h3v);
            *(uint2*)((u32*)outv + (size_t)n * 64 + w32 * 2) = pw;
        }
    } else {
        // logits: lane w32 holds features 4*w32 .. 4*w32+3; Wl is [128][2]
        float4 q0 = *(const float4*)&Wl[w32 * 8];
        float4 q1 = *(const float4*)&Wl[w32 * 8 + 4];
        float p0 = h0v * q0.x + h1v * q0.z + h2v * q1.x + h3v * q1.z;
        float p1 = h0v * q0.y + h1v * q0.w + h2v * q1.y + h3v * q1.w;
#pragma unroll
        for (int off = 16; off > 0; off >>= 1) {
            p0 += __shfl_down(p0, off);
            p1 += __shfl_down(p1, off);
        }
        if (lane == 0) {
            float z0 = p0 + bl[0], z1 = p1 + bl[1];
            float m = fmaxf(z0, z1);
            float ls = m + logf(expf(z0 - m) + expf(z1 - m));
            float* out = (float*)outv;
            out[(size_t)n * 2 + 0] = z0 - ls;
            out[(size_t)n * 2 + 1] = z1 - ls;
        }
    }
}

// ---------------- launch ----------------

extern "C" void kernel_launch(void* const* d_in, const int* in_sizes, int n_in,
                              void* d_out, int out_size, void* d_ws, size_t ws_size,
                              hipStream_t stream) {
    const float* high  = (const float*)d_in[0];
    const float* low   = (const float*)d_in[1];
    const int*   ei    = (const int*)d_in[2];
    const float* W_emb = (const float*)d_in[3];
    const float* b_emb = (const float*)d_in[4];
    const float* W1    = (const float*)d_in[5];
    const float* b1    = (const float*)d_in[6];
    const float* W2    = (const float*)d_in[7];
    const float* b2    = (const float*)d_in[8];
    const float* Wl    = (const float*)d_in[9];
    const float* bl    = (const float*)d_in[10];

    int N = in_sizes[0] / HIGH;
    int E = in_sizes[2] / 2;
    const int* srcp = ei;
    const int* dstp = ei + E;
    float* out = (float*)d_out;

    int NB = (N + 255) >> BINSHIFT;
    int NSCAN = NB * NBLK;

    char* ws = (char*)d_ws;
    size_t off = 0;
    auto alloc = [&](size_t b) { size_t o = off; off += (b + 255) & ~(size_t)255; return o; };
    float* dis       = (float*)(ws + alloc((size_t)N * 4));
    int*   cnt       = (int*)  (ws + alloc((size_t)N * 4));
    int*   row_start = (int*)  (ws + alloc((size_t)(N + 1) * 4));
    int*   bsums     = (int*)  (ws + alloc(4096));
    int*   cnts      = (int*)  (ws + alloc((size_t)NSCAN * 4));
    u32*   packed    = (u32*)  (ws + alloc((size_t)E * 4));
    int*   csr       = (int*)  (ws + alloc((size_t)E * 4));
    u16*   Wt1       = (u16*)  (ws + alloc((size_t)512 * 128 * 2));
    u16*   Wt2       = (u16*)  (ws + alloc((size_t)128 * 128 * 2));
    u16*   WtE       = (u16*)  (ws + alloc((size_t)64 * 128 * 2));
    u16*   bufE      = (u16*)  (ws + alloc((size_t)N * 128 * 2));  // bf16 low_emb
    u8*    bufX      = (u8*)   (ws + alloc((size_t)N * 128));      // fp8 xls
    u16*   bufH      = (u16*)  (ws + alloc((size_t)N * 128 * 2));  // bf16 h1
    (void)ws_size; (void)n_in; (void)out_size;

    int nbS = (NSCAN + 1023) / 1024;
    int nbN = (N + 1023) / 1024;
    int mt  = (N + 63) / 64;

    // ---- weight transpose+cast (one kernel) ----
    k_castw_all<<<(90112 + 255) / 256, 256, 0, stream>>>(W1, Wt1, W2, Wt2, W_emb, WtE);

    // ---- binned CSR build ----
    k_binhist<<<NBLK, 256, 0, stream>>>(dstp, E, cnts, NB);
    k_scan1<<<nbS, 256, 0, stream>>>(cnts, NSCAN, bsums);
    k_scan2<<<1, 64, 0, stream>>>(bsums, nbS);
    k_scan3_flat<<<nbS, 256, 0, stream>>>(cnts, NSCAN, bsums);
    k_binscatter<<<NBLK, 256, 0, stream>>>(srcp, dstp, E, cnts, packed, NB);
    k_hist2<<<NB, 256, 0, stream>>>(packed, cnts, E, cnt, NB, N);
    k_dis<<<(N + 255) / 256, 256, 0, stream>>>(cnt, dis, N);
    k_scan1<<<nbN, 256, 0, stream>>>(cnt, N, bsums);
    k_scan2<<<1, 64, 0, stream>>>(bsums, nbN);
    k_scan3_rows<<<nbN, 256, 0, stream>>>(cnt, N, bsums, row_start, E);
    k_fill2<<<NB, 256, 0, stream>>>(packed, cnts, E, row_start, csr, NB, N);

    // ---- network ----
    // low_emb = relu(low @ W_emb + b_emb)                 -> bufE (bf16)
    k_mgemm<false, true, true, false, 0><<<mt, 256, 0, stream>>>(
        low, LOWD, (const u32*)bufE, 0, WtE, b_emb, nullptr, bufE, N);
    // xls1 = ([high | low_emb] @ W1) * dis                -> bufX (fp8)
    k_mgemm<false, false, false, true, 1><<<mt, 256, 0, stream>>>(
        high, HIGH, (const u32*)bufE, EMB, Wt1, nullptr, dis, bufX, N);
    // h1 = relu(dis * (gather(xls1) + self) + b1)         -> bufH (bf16)
    k_gatherw<0><<<(N + 3) / 4, 256, 0, stream>>>(
        (const u32*)bufX, row_start, csr, dis, b1, nullptr, nullptr, bufH, N);
    // xls2 = (h1 @ W2) * dis                              -> bufX (fp8)
    k_mgemm<true, false, false, true, 1><<<mt, 256, 0, stream>>>(
        bufH, HID, (const u32*)bufH, 0, Wt2, nullptr, dis, bufX, N);
    // out = log_softmax((dis * (gather(xls2) + self) + b2) @ W_lin + b_lin)  [fused]
    k_gatherw<1><<<(N + 3) / 4, 256, 0, stream>>>(
        (const u32*)bufX, row_start, csr, dis, b2, Wl, bl, out, N);
}